// Round 1
// baseline (2132.759 us; speedup 1.0000x reference)
//
#include <hip/hip_runtime.h>
#include <hip/hip_bf16.h>
#include <math.h>

#define BB 2
#define LL 1024
#define DMODEL 1024
#define DINNER 2048
#define NHEADS_ 16
#define HEADDIM_ 128
#define DSTATE 64
#define CONVDIM 2176
#define DINPROJ 4240

// ---------------- fp32 SGEMM:  C[m,n] = sum_k A[m,k] * Bm[n,k]  (B given N x K, i.e. B^T) ----------
__global__ __launch_bounds__(256) void sgemm_nt(const float* __restrict__ A,
                                                const float* __restrict__ Bm,
                                                float* __restrict__ C,
                                                int M, int N, int K) {
  __shared__ float As[8][128];
  __shared__ float Bs[8][128];
  const int t = threadIdx.x;
  const int bm = blockIdx.y * 128;
  const int bn = blockIdx.x * 128;
  const int lr = t >> 1;          // 0..127 row of tile being loaded
  const int lk = (t & 1) * 4;     // k sub-offset
  const int tm = (t & 15) * 8;    // micro-tile row base
  const int tn = (t >> 4) * 8;    // micro-tile col base
  float acc[8][8];
#pragma unroll
  for (int i = 0; i < 8; ++i)
#pragma unroll
    for (int j = 0; j < 8; ++j) acc[i][j] = 0.f;

  for (int k0 = 0; k0 < K; k0 += 8) {
    float4 av = make_float4(0.f, 0.f, 0.f, 0.f);
    float4 bv = make_float4(0.f, 0.f, 0.f, 0.f);
    const int am = bm + lr;
    if (am < M) av = *(const float4*)(A + (size_t)am * K + k0 + lk);
    const int bnr = bn + lr;
    if (bnr < N) bv = *(const float4*)(Bm + (size_t)bnr * K + k0 + lk);
    __syncthreads();
    As[lk + 0][lr] = av.x; As[lk + 1][lr] = av.y; As[lk + 2][lr] = av.z; As[lk + 3][lr] = av.w;
    Bs[lk + 0][lr] = bv.x; Bs[lk + 1][lr] = bv.y; Bs[lk + 2][lr] = bv.z; Bs[lk + 3][lr] = bv.w;
    __syncthreads();
#pragma unroll
    for (int kk = 0; kk < 8; ++kk) {
      float4 a0 = *(const float4*)&As[kk][tm];
      float4 a1 = *(const float4*)&As[kk][tm + 4];
      float4 b0 = *(const float4*)&Bs[kk][tn];
      float4 b1 = *(const float4*)&Bs[kk][tn + 4];
      float ar[8] = {a0.x, a0.y, a0.z, a0.w, a1.x, a1.y, a1.z, a1.w};
      float br[8] = {b0.x, b0.y, b0.z, b0.w, b1.x, b1.y, b1.z, b1.w};
#pragma unroll
      for (int i = 0; i < 8; ++i)
#pragma unroll
        for (int j = 0; j < 8; ++j) acc[i][j] = fmaf(ar[i], br[j], acc[i][j]);
    }
  }
#pragma unroll
  for (int i = 0; i < 8; ++i) {
    const int row = bm + tm + i;
    if (row >= M) continue;
    const int col = bn + tn;
    if (col + 7 < N) {
      float4 c0 = make_float4(acc[i][0], acc[i][1], acc[i][2], acc[i][3]);
      float4 c1 = make_float4(acc[i][4], acc[i][5], acc[i][6], acc[i][7]);
      *(float4*)(C + (size_t)row * N + col) = c0;
      *(float4*)(C + (size_t)row * N + col + 4) = c1;
    } else {
#pragma unroll
      for (int j = 0; j < 8; ++j)
        if (col + j < N) C[(size_t)row * N + col + j] = acc[i][j];
    }
  }
}

// ---------------- causal depthwise conv(4) + bias + SiLU, with channel split ----------------
__global__ __launch_bounds__(256) void conv_silu(const float* __restrict__ zx,
                                                 const float* __restrict__ conv_w,
                                                 const float* __restrict__ conv_b,
                                                 float* __restrict__ xy,
                                                 float* __restrict__ Bm,
                                                 float* __restrict__ Cm) {
  const int idx = blockIdx.x * 256 + threadIdx.x;
  if (idx >= BB * LL * CONVDIM) return;
  const int c = idx % CONVDIM;
  const int bl = idx / CONVDIM;
  const int l = bl & (LL - 1);
  const float w0 = conv_w[c * 4 + 0], w1 = conv_w[c * 4 + 1];
  const float w2 = conv_w[c * 4 + 2], w3 = conv_w[c * 4 + 3];
  const float* base = zx + (size_t)bl * DINPROJ + DINNER + c;
  float acc = conv_b[c];
  acc = fmaf(base[0], w3, acc);                                  // tap at l
  if (l >= 1) acc = fmaf(base[-1 * DINPROJ], w2, acc);
  if (l >= 2) acc = fmaf(base[-2 * DINPROJ], w1, acc);
  if (l >= 3) acc = fmaf(base[-3 * DINPROJ], w0, acc);
  const float s = acc / (1.f + expf(-acc));
  if (c < DINNER)                    xy[(size_t)bl * DINNER + c] = s;
  else if (c < DINNER + DSTATE)      Bm[bl * DSTATE + (c - DINNER)] = s;
  else                               Cm[bl * DSTATE + (c - DINNER - DSTATE)] = s;
}

// ---------------- dt = softplus(raw + bias); dA = exp(dt * (-exp(A_log))) ----------------
__global__ __launch_bounds__(256) void dt_kernel(const float* __restrict__ zx,
                                                 const float* __restrict__ dt_bias,
                                                 const float* __restrict__ A_log,
                                                 float* __restrict__ dtv,
                                                 float* __restrict__ dAv) {
  const int idx = blockIdx.x * 256 + threadIdx.x;
  if (idx >= BB * LL * NHEADS_) return;
  const int h = idx & (NHEADS_ - 1);
  const int bl = idx >> 4;
  const float x = zx[(size_t)bl * DINPROJ + (DINNER + CONVDIM) + h] + dt_bias[h];
  const float sp = (x > 20.f) ? x : log1pf(expf(x));
  dtv[idx] = sp;
  const float A = -expf(A_log[h]);
  dAv[idx] = expf(sp * A);
}

// ---------------- sequential SSM scan, one block per (b, head), h-state in registers ----------------
__global__ __launch_bounds__(128) void scan_kernel(float* __restrict__ xy,
                                                   const float* __restrict__ Bm,
                                                   const float* __restrict__ Cm,
                                                   const float* __restrict__ dtv,
                                                   const float* __restrict__ dAv,
                                                   const float* __restrict__ Dp_) {
  const int b = blockIdx.x >> 4;
  const int h = blockIdx.x & (NHEADS_ - 1);
  const int p = threadIdx.x;      // 0..127 head-dim index
  float hreg[DSTATE];
#pragma unroll
  for (int n = 0; n < DSTATE; ++n) hreg[n] = 0.f;
  const float Dp = Dp_[h];
  float* xp = xy + (size_t)b * LL * DINNER + h * HEADDIM_ + p;
  const float* dtp = dtv + b * LL * NHEADS_ + h;
  const float* dAp = dAv + b * LL * NHEADS_ + h;
  const float* Bp = Bm + (size_t)b * LL * DSTATE;
  const float* Cp = Cm + (size_t)b * LL * DSTATE;
  for (int t = 0; t < LL; ++t) {
    const float x = xp[(size_t)t * DINNER];
    const float dt_t = dtp[t * NHEADS_];
    const float dA_t = dAp[t * NHEADS_];
    const float u = dt_t * x;
    const float* Bt = Bp + t * DSTATE;
    const float* Ct = Cp + t * DSTATE;
    float a0 = 0.f, a1 = 0.f, a2 = 0.f, a3 = 0.f;
#pragma unroll
    for (int n = 0; n < DSTATE; n += 4) {
      const float4 b4 = *(const float4*)(Bt + n);
      const float4 c4 = *(const float4*)(Ct + n);
      hreg[n + 0] = fmaf(dA_t, hreg[n + 0], u * b4.x); a0 = fmaf(hreg[n + 0], c4.x, a0);
      hreg[n + 1] = fmaf(dA_t, hreg[n + 1], u * b4.y); a1 = fmaf(hreg[n + 1], c4.y, a1);
      hreg[n + 2] = fmaf(dA_t, hreg[n + 2], u * b4.z); a2 = fmaf(hreg[n + 2], c4.z, a2);
      hreg[n + 3] = fmaf(dA_t, hreg[n + 3], u * b4.w); a3 = fmaf(hreg[n + 3], c4.w, a3);
    }
    xp[(size_t)t * DINNER] = (a0 + a1) + (a2 + a3) + Dp * x;   // y (in-place over x)
  }
}

// ---------------- y *= silu(z); RMSNorm(y) * norm_w  (in-place on xy) ----------------
__global__ __launch_bounds__(256) void gate_norm(float* __restrict__ xy,
                                                 const float* __restrict__ zx,
                                                 const float* __restrict__ nw) {
  __shared__ float red[4];
  const int row = blockIdx.x;
  const int t = threadIdx.x;
  float* yrow = xy + (size_t)row * DINNER;
  const float* zrow = zx + (size_t)row * DINPROJ;
  float v[8];
  float ss = 0.f;
#pragma unroll
  for (int q = 0; q < 2; ++q) {
    const int e = q * 1024 + t * 4;
    const float4 y4 = *(const float4*)(yrow + e);
    const float4 z4 = *(const float4*)(zrow + e);
    float r0 = y4.x * (z4.x / (1.f + expf(-z4.x)));
    float r1 = y4.y * (z4.y / (1.f + expf(-z4.y)));
    float r2 = y4.z * (z4.z / (1.f + expf(-z4.z)));
    float r3 = y4.w * (z4.w / (1.f + expf(-z4.w)));
    v[q * 4 + 0] = r0; v[q * 4 + 1] = r1; v[q * 4 + 2] = r2; v[q * 4 + 3] = r3;
    ss += r0 * r0 + r1 * r1 + r2 * r2 + r3 * r3;
  }
#pragma unroll
  for (int off = 32; off; off >>= 1) ss += __shfl_down(ss, off);
  const int lane = t & 63, wid = t >> 6;
  if (lane == 0) red[wid] = ss;
  __syncthreads();
  const float tot = red[0] + red[1] + red[2] + red[3];
  const float rstd = rsqrtf(tot * (1.f / DINNER) + 1e-5f);
#pragma unroll
  for (int q = 0; q < 2; ++q) {
    const int e = q * 1024 + t * 4;
    const float4 w4 = *(const float4*)(nw + e);
    float4 o;
    o.x = v[q * 4 + 0] * rstd * w4.x;
    o.y = v[q * 4 + 1] * rstd * w4.y;
    o.z = v[q * 4 + 2] * rstd * w4.z;
    o.w = v[q * 4 + 3] * rstd * w4.w;
    *(float4*)(yrow + e) = o;
  }
}

extern "C" void kernel_launch(void* const* d_in, const int* in_sizes, int n_in,
                              void* d_out, int out_size, void* d_ws, size_t ws_size,
                              hipStream_t stream) {
  const float* hs      = (const float*)d_in[0];
  const float* W_in    = (const float*)d_in[1];
  const float* conv_w  = (const float*)d_in[2];
  const float* conv_b  = (const float*)d_in[3];
  const float* dt_bias = (const float*)d_in[4];
  const float* A_log   = (const float*)d_in[5];
  const float* D_param = (const float*)d_in[6];
  const float* norm_w  = (const float*)d_in[7];
  const float* W_out   = (const float*)d_in[8];
  float* out = (float*)d_out;

  float* ws  = (float*)d_ws;
  float* zx  = ws;                                     // (B*L, 4240)
  float* xy  = zx + (size_t)BB * LL * DINPROJ;         // (B*L, 2048): x after conv, y after scan
  float* Bm  = xy + (size_t)BB * LL * DINNER;          // (B*L, 64)
  float* Cm  = Bm + (size_t)BB * LL * DSTATE;          // (B*L, 64)
  float* dtv = Cm + (size_t)BB * LL * DSTATE;          // (B*L, 16)
  float* dAv = dtv + (size_t)BB * LL * NHEADS_;        // (B*L, 16)

  const int M = BB * LL;

  sgemm_nt<<<dim3((DINPROJ + 127) / 128, M / 128), 256, 0, stream>>>(hs, W_in, zx, M, DINPROJ, DMODEL);
  conv_silu<<<(BB * LL * CONVDIM + 255) / 256, 256, 0, stream>>>(zx, conv_w, conv_b, xy, Bm, Cm);
  dt_kernel<<<(BB * LL * NHEADS_ + 255) / 256, 256, 0, stream>>>(zx, dt_bias, A_log, dtv, dAv);
  scan_kernel<<<BB * NHEADS_, 128, 0, stream>>>(xy, Bm, Cm, dtv, dAv, D_param);
  gate_norm<<<M, 256, 0, stream>>>(xy, zx, norm_w);
  sgemm_nt<<<dim3(DMODEL / 128, M / 128), 256, 0, stream>>>(xy, W_out, out, M, DMODEL, DINNER);
}

// Round 2
// 649.042 us; speedup vs baseline: 3.2860x; 3.2860x over previous
//
#include <hip/hip_runtime.h>
#include <hip/hip_bf16.h>
#include <math.h>

#define BB 2
#define LL 1024
#define DMODEL 1024
#define DINNER 2048
#define NH 16
#define HD 128
#define NS 64
#define CONVDIM 2176
#define DINPROJ 4240
#define QC 64
#define NCH 16

// ---------------- fp32 SGEMM:  C[m,n] = sum_k A[m,k] * Bm[n,k]  (B given N x K, i.e. B^T) ----------
__global__ __launch_bounds__(256) void sgemm_nt(const float* __restrict__ A,
                                                const float* __restrict__ Bm,
                                                float* __restrict__ C,
                                                int M, int N, int K) {
  __shared__ float As[8][128];
  __shared__ float Bs[8][128];
  const int t = threadIdx.x;
  const int bm = blockIdx.y * 128;
  const int bn = blockIdx.x * 128;
  const int lr = t >> 1;
  const int lk = (t & 1) * 4;
  const int tm = (t & 15) * 8;
  const int tn = (t >> 4) * 8;
  float acc[8][8];
#pragma unroll
  for (int i = 0; i < 8; ++i)
#pragma unroll
    for (int j = 0; j < 8; ++j) acc[i][j] = 0.f;

  for (int k0 = 0; k0 < K; k0 += 8) {
    float4 av = make_float4(0.f, 0.f, 0.f, 0.f);
    float4 bv = make_float4(0.f, 0.f, 0.f, 0.f);
    const int am = bm + lr;
    if (am < M) av = *(const float4*)(A + (size_t)am * K + k0 + lk);
    const int bnr = bn + lr;
    if (bnr < N) bv = *(const float4*)(Bm + (size_t)bnr * K + k0 + lk);
    __syncthreads();
    As[lk + 0][lr] = av.x; As[lk + 1][lr] = av.y; As[lk + 2][lr] = av.z; As[lk + 3][lr] = av.w;
    Bs[lk + 0][lr] = bv.x; Bs[lk + 1][lr] = bv.y; Bs[lk + 2][lr] = bv.z; Bs[lk + 3][lr] = bv.w;
    __syncthreads();
#pragma unroll
    for (int kk = 0; kk < 8; ++kk) {
      float4 a0 = *(const float4*)&As[kk][tm];
      float4 a1 = *(const float4*)&As[kk][tm + 4];
      float4 b0 = *(const float4*)&Bs[kk][tn];
      float4 b1 = *(const float4*)&Bs[kk][tn + 4];
      float ar[8] = {a0.x, a0.y, a0.z, a0.w, a1.x, a1.y, a1.z, a1.w};
      float br[8] = {b0.x, b0.y, b0.z, b0.w, b1.x, b1.y, b1.z, b1.w};
#pragma unroll
      for (int i = 0; i < 8; ++i)
#pragma unroll
        for (int j = 0; j < 8; ++j) acc[i][j] = fmaf(ar[i], br[j], acc[i][j]);
    }
  }
#pragma unroll
  for (int i = 0; i < 8; ++i) {
    const int row = bm + tm + i;
    if (row >= M) continue;
    const int col = bn + tn;
    if (col + 7 < N) {
      float4 c0 = make_float4(acc[i][0], acc[i][1], acc[i][2], acc[i][3]);
      float4 c1 = make_float4(acc[i][4], acc[i][5], acc[i][6], acc[i][7]);
      *(float4*)(C + (size_t)row * N + col) = c0;
      *(float4*)(C + (size_t)row * N + col + 4) = c1;
    } else {
#pragma unroll
      for (int j = 0; j < 8; ++j)
        if (col + j < N) C[(size_t)row * N + col + j] = acc[i][j];
    }
  }
}

// ---------------- causal depthwise conv(4) + bias + SiLU, with channel split ----------------
__global__ __launch_bounds__(256) void conv_silu(const float* __restrict__ zx,
                                                 const float* __restrict__ conv_w,
                                                 const float* __restrict__ conv_b,
                                                 float* __restrict__ xy,
                                                 float* __restrict__ Bm,
                                                 float* __restrict__ Cm) {
  const int idx = blockIdx.x * 256 + threadIdx.x;
  if (idx >= BB * LL * CONVDIM) return;
  const int c = idx % CONVDIM;
  const int bl = idx / CONVDIM;
  const int l = bl & (LL - 1);
  const float w0 = conv_w[c * 4 + 0], w1 = conv_w[c * 4 + 1];
  const float w2 = conv_w[c * 4 + 2], w3 = conv_w[c * 4 + 3];
  const float* base = zx + (size_t)bl * DINPROJ + DINNER + c;
  float acc = conv_b[c];
  acc = fmaf(base[0], w3, acc);
  if (l >= 1) acc = fmaf(base[-1 * DINPROJ], w2, acc);
  if (l >= 2) acc = fmaf(base[-2 * DINPROJ], w1, acc);
  if (l >= 3) acc = fmaf(base[-3 * DINPROJ], w0, acc);
  const float s = acc / (1.f + expf(-acc));
  if (c < DINNER)                    xy[(size_t)bl * DINNER + c] = s;
  else if (c < DINNER + NS)          Bm[bl * NS + (c - DINNER)] = s;
  else                               Cm[bl * NS + (c - DINNER - NS)] = s;
}

// ---------------- dt = softplus(raw + bias) ----------------
__global__ __launch_bounds__(256) void dt_kernel(const float* __restrict__ zx,
                                                 const float* __restrict__ dt_bias,
                                                 float* __restrict__ dtv) {
  const int idx = blockIdx.x * 256 + threadIdx.x;
  if (idx >= BB * LL * NH) return;
  const int h = idx & (NH - 1);
  const int bl = idx >> 4;
  const float x = zx[(size_t)bl * DINPROJ + (DINNER + CONVDIM) + h] + dt_bias[h];
  const float sp = (x > 20.f) ? x : log1pf(expf(x));
  dtv[idx] = sp;
}

// ---------------- within-chunk cumulative log-decay: clog[(b,h,t)] = sum_{s=chunk_start..t} dt_s*A_h ----
__global__ __launch_bounds__(256) void cumlog_kernel(const float* __restrict__ dtv,
                                                     const float* __restrict__ A_log,
                                                     float* __restrict__ clog) {
  const int idx = blockIdx.x * 256 + threadIdx.x;   // (bh*16 + c), 512 total
  if (idx >= BB * NH * NCH) return;
  const int c = idx & (NCH - 1);
  const int bh = idx >> 4;
  const int b = bh >> 4, h = bh & (NH - 1);
  const float A = -__expf(A_log[h]);
  float run = 0.f;
  for (int i = 0; i < QC; ++i) {
    run += A * dtv[(size_t)(b * LL + c * QC + i) * NH + h];
    clog[(size_t)bh * LL + c * QC + i] = run;
  }
}

// ---------------- SSD intra-chunk: y_intra and chunk-state S, one block per (b,h,chunk) -------------
__global__ __launch_bounds__(256) void ssd_intra(const float* __restrict__ xy,
                                                 const float* __restrict__ Bm,
                                                 const float* __restrict__ Cm,
                                                 const float* __restrict__ dtv,
                                                 const float* __restrict__ clog,
                                                 float* __restrict__ zx,   // y_intra into dead cols
                                                 float* __restrict__ S) {
  __shared__ float sBT[NS][QC];   // [n][s]
  __shared__ float sCT[NS][QC];   // [n][t]
  __shared__ float sB[QC][NS];    // [s][n]
  __shared__ float su[QC][HD];    // [s][p]  u = dt*x
  __shared__ float sPT[QC][QC];   // [s][t]  masked weights
  __shared__ float scl[QC];
  __shared__ float swend[QC];
  const int blk = blockIdx.x;
  const int bh = blk >> 4, c = blk & (NCH - 1);
  const int b = bh >> 4, h = bh & (NH - 1);
  const int t0 = c * QC;
  const int tid = threadIdx.x;

  const float* Bg = Bm + (size_t)(b * LL + t0) * NS;
  const float* Cg = Cm + (size_t)(b * LL + t0) * NS;
#pragma unroll
  for (int j = 0; j < 4; ++j) {
    const int e = j * 1024 + tid * 4;
    const int r = e >> 6, n = e & 63;
    const float4 bv = *(const float4*)(Bg + e);
    const float4 cv = *(const float4*)(Cg + e);
    sB[r][n] = bv.x; sB[r][n + 1] = bv.y; sB[r][n + 2] = bv.z; sB[r][n + 3] = bv.w;
    sBT[n][r] = bv.x; sBT[n + 1][r] = bv.y; sBT[n + 2][r] = bv.z; sBT[n + 3][r] = bv.w;
    sCT[n][r] = cv.x; sCT[n + 1][r] = cv.y; sCT[n + 2][r] = cv.z; sCT[n + 3][r] = cv.w;
  }
#pragma unroll
  for (int j = 0; j < 8; ++j) {
    const int e = j * 1024 + tid * 4;
    const int s = e >> 7, p = e & 127;
    const float dt = dtv[(size_t)(b * LL + t0 + s) * NH + h];
    const float4 xv = *(const float4*)(xy + (size_t)(b * LL + t0 + s) * DINNER + h * HD + p);
    su[s][p] = dt * xv.x; su[s][p + 1] = dt * xv.y; su[s][p + 2] = dt * xv.z; su[s][p + 3] = dt * xv.w;
  }
  if (tid < QC) scl[tid] = clog[(size_t)bh * LL + t0 + tid];
  __syncthreads();
  if (tid < QC) swend[tid] = __expf(scl[QC - 1] - scl[tid]);

  // phase 1: P^T[s][t] = (s<=t) ? exp(cl[t]-cl[s]) * sum_n C[t][n]B[s][n] : 0
  {
    const int tb = (tid >> 4) * 4;
    const int sb = (tid & 15) * 4;
    float g[4][4] = {};
#pragma unroll 8
    for (int n = 0; n < NS; ++n) {
      const float4 cv = *(const float4*)&sCT[n][tb];
      const float4 bv = *(const float4*)&sBT[n][sb];
      const float cr[4] = {cv.x, cv.y, cv.z, cv.w};
      const float br[4] = {bv.x, bv.y, bv.z, bv.w};
#pragma unroll
      for (int i = 0; i < 4; ++i)
#pragma unroll
        for (int j = 0; j < 4; ++j) g[i][j] = fmaf(cr[i], br[j], g[i][j]);
    }
#pragma unroll
    for (int i = 0; i < 4; ++i) {
      const int t = tb + i;
      const float cl_t = scl[t];
#pragma unroll
      for (int j = 0; j < 4; ++j) {
        const int s = sb + j;
        sPT[s][t] = (s <= t) ? g[i][j] * __expf(cl_t - scl[s]) : 0.f;
      }
    }
  }
  __syncthreads();

  // phase 2: y_intra[t][p] = sum_s P^T[s][t] * u[s][p]
  {
    const int tq = (tid >> 4) * 4;
    const int pb = (tid & 15) * 8;
    float acc[4][8] = {};
    for (int s = 0; s < QC; ++s) {
      const float4 w4 = *(const float4*)&sPT[s][tq];
      const float4 u0 = *(const float4*)&su[s][pb];
      const float4 u1 = *(const float4*)&su[s][pb + 4];
      const float wr[4] = {w4.x, w4.y, w4.z, w4.w};
      const float ur[8] = {u0.x, u0.y, u0.z, u0.w, u1.x, u1.y, u1.z, u1.w};
#pragma unroll
      for (int i = 0; i < 4; ++i)
#pragma unroll
        for (int j = 0; j < 8; ++j) acc[i][j] = fmaf(wr[i], ur[j], acc[i][j]);
    }
#pragma unroll
    for (int i = 0; i < 4; ++i) {
      float* yp = zx + (size_t)(b * LL + t0 + tq + i) * DINPROJ + DINNER + h * HD + pb;
      *(float4*)yp       = make_float4(acc[i][0], acc[i][1], acc[i][2], acc[i][3]);
      *(float4*)(yp + 4) = make_float4(acc[i][4], acc[i][5], acc[i][6], acc[i][7]);
    }
  }

  // phase 3: S_c[p][n] = sum_s wend[s] * u[s][p] * B[s][n]
  {
    const int p0 = (tid >> 3) * 4;
    const int nb = (tid & 7) * 8;
    float acc[4][8] = {};
    for (int s = 0; s < QC; ++s) {
      const float w = swend[s];
      const float4 uv = *(const float4*)&su[s][p0];
      const float4 b0 = *(const float4*)&sB[s][nb];
      const float4 b1 = *(const float4*)&sB[s][nb + 4];
      const float ur[4] = {uv.x * w, uv.y * w, uv.z * w, uv.w * w};
      const float br[8] = {b0.x, b0.y, b0.z, b0.w, b1.x, b1.y, b1.z, b1.w};
#pragma unroll
      for (int i = 0; i < 4; ++i)
#pragma unroll
        for (int j = 0; j < 8; ++j) acc[i][j] = fmaf(ur[i], br[j], acc[i][j]);
    }
    float* Sg = S + (size_t)blk * (HD * NS);
#pragma unroll
    for (int i = 0; i < 4; ++i) {
      float* sp = Sg + (size_t)(p0 + i) * NS + nb;
      *(float4*)sp       = make_float4(acc[i][0], acc[i][1], acc[i][2], acc[i][3]);
      *(float4*)(sp + 4) = make_float4(acc[i][4], acc[i][5], acc[i][6], acc[i][7]);
    }
  }
}

// ---------------- inter-chunk scan over chunk states (in place: S[c] becomes H_prev for chunk c) ----
__global__ __launch_bounds__(256) void ssd_scan(float* __restrict__ S,
                                                const float* __restrict__ clog) {
  const int idx = blockIdx.x * 256 + threadIdx.x;    // (bh, p, n) : 2*16*128*64
  const int pn = idx & (HD * NS - 1);
  const int bh = idx >> 13;
  float* Sp = S + (size_t)bh * NCH * (HD * NS) + pn;
  const float* cl = clog + (size_t)bh * LL;
  float H = 0.f;
#pragma unroll
  for (int c = 0; c < NCH; ++c) {
    const float dec = __expf(cl[c * QC + QC - 1]);
    const float s = Sp[(size_t)c * (HD * NS)];
    Sp[(size_t)c * (HD * NS)] = H;
    H = dec * H + s;
  }
}

// ---------------- y[t][p] = y_intra + exp(cl[t]) * sum_n C[t][n] Hprev[p][n] + D*x, in place on xy ---
__global__ __launch_bounds__(256) void ssd_out(float* __restrict__ xy,
                                               const float* __restrict__ zx,
                                               const float* __restrict__ Cm,
                                               const float* __restrict__ clog,
                                               const float* __restrict__ S,
                                               const float* __restrict__ Dp_) {
  __shared__ float sHT[NS][HD];   // [n][p]
  __shared__ float sCT[NS][QC];   // [n][t]
  __shared__ float scl[QC];
  const int blk = blockIdx.x;
  const int bh = blk >> 4, c = blk & (NCH - 1);
  const int b = bh >> 4, h = bh & (NH - 1);
  const int t0 = c * QC;
  const int tid = threadIdx.x;
  const float* Hg = S + (size_t)blk * (HD * NS);
#pragma unroll
  for (int j = 0; j < 8; ++j) {
    const int e = j * 1024 + tid * 4;
    const int p = e >> 6, n = e & 63;
    const float4 hv = *(const float4*)(Hg + e);
    sHT[n][p] = hv.x; sHT[n + 1][p] = hv.y; sHT[n + 2][p] = hv.z; sHT[n + 3][p] = hv.w;
  }
  const float* Cg = Cm + (size_t)(b * LL + t0) * NS;
#pragma unroll
  for (int j = 0; j < 4; ++j) {
    const int e = j * 1024 + tid * 4;
    const int r = e >> 6, n = e & 63;
    const float4 cv = *(const float4*)(Cg + e);
    sCT[n][r] = cv.x; sCT[n + 1][r] = cv.y; sCT[n + 2][r] = cv.z; sCT[n + 3][r] = cv.w;
  }
  if (tid < QC) scl[tid] = clog[(size_t)bh * LL + t0 + tid];
  __syncthreads();
  const int tq = (tid >> 4) * 4;
  const int pb = (tid & 15) * 8;
  float acc[4][8] = {};
  for (int n = 0; n < NS; ++n) {
    const float4 cv = *(const float4*)&sCT[n][tq];
    const float4 h0 = *(const float4*)&sHT[n][pb];
    const float4 h1 = *(const float4*)&sHT[n][pb + 4];
    const float cr[4] = {cv.x, cv.y, cv.z, cv.w};
    const float hr[8] = {h0.x, h0.y, h0.z, h0.w, h1.x, h1.y, h1.z, h1.w};
#pragma unroll
    for (int i = 0; i < 4; ++i)
#pragma unroll
      for (int j = 0; j < 8; ++j) acc[i][j] = fmaf(cr[i], hr[j], acc[i][j]);
  }
  const float Dv = Dp_[h];
#pragma unroll
  for (int i = 0; i < 4; ++i) {
    const int t = tq + i;
    const float sc = __expf(scl[t]);
    const size_t row = (size_t)(b * LL + t0 + t);
    const float* yp = zx + row * DINPROJ + DINNER + h * HD + pb;
    float* xp = xy + row * DINNER + h * HD + pb;
    const float4 y0 = *(const float4*)yp, y1 = *(const float4*)(yp + 4);
    const float4 x0 = *(const float4*)xp, x1 = *(const float4*)(xp + 4);
    float4 o0, o1;
    o0.x = y0.x + sc * acc[i][0] + Dv * x0.x;
    o0.y = y0.y + sc * acc[i][1] + Dv * x0.y;
    o0.z = y0.z + sc * acc[i][2] + Dv * x0.z;
    o0.w = y0.w + sc * acc[i][3] + Dv * x0.w;
    o1.x = y1.x + sc * acc[i][4] + Dv * x1.x;
    o1.y = y1.y + sc * acc[i][5] + Dv * x1.y;
    o1.z = y1.z + sc * acc[i][6] + Dv * x1.z;
    o1.w = y1.w + sc * acc[i][7] + Dv * x1.w;
    *(float4*)xp = o0;
    *(float4*)(xp + 4) = o1;
  }
}

// ---------------- y *= silu(z); RMSNorm(y) * norm_w  (in-place on xy) ----------------
__global__ __launch_bounds__(256) void gate_norm(float* __restrict__ xy,
                                                 const float* __restrict__ zx,
                                                 const float* __restrict__ nw) {
  __shared__ float red[4];
  const int row = blockIdx.x;
  const int t = threadIdx.x;
  float* yrow = xy + (size_t)row * DINNER;
  const float* zrow = zx + (size_t)row * DINPROJ;
  float v[8];
  float ss = 0.f;
#pragma unroll
  for (int q = 0; q < 2; ++q) {
    const int e = q * 1024 + t * 4;
    const float4 y4 = *(const float4*)(yrow + e);
    const float4 z4 = *(const float4*)(zrow + e);
    float r0 = y4.x * (z4.x / (1.f + expf(-z4.x)));
    float r1 = y4.y * (z4.y / (1.f + expf(-z4.y)));
    float r2 = y4.z * (z4.z / (1.f + expf(-z4.z)));
    float r3 = y4.w * (z4.w / (1.f + expf(-z4.w)));
    v[q * 4 + 0] = r0; v[q * 4 + 1] = r1; v[q * 4 + 2] = r2; v[q * 4 + 3] = r3;
    ss += r0 * r0 + r1 * r1 + r2 * r2 + r3 * r3;
  }
#pragma unroll
  for (int off = 32; off; off >>= 1) ss += __shfl_down(ss, off);
  const int lane = t & 63, wid = t >> 6;
  if (lane == 0) red[wid] = ss;
  __syncthreads();
  const float tot = red[0] + red[1] + red[2] + red[3];
  const float rstd = rsqrtf(tot * (1.f / DINNER) + 1e-5f);
#pragma unroll
  for (int q = 0; q < 2; ++q) {
    const int e = q * 1024 + t * 4;
    const float4 w4 = *(const float4*)(nw + e);
    float4 o;
    o.x = v[q * 4 + 0] * rstd * w4.x;
    o.y = v[q * 4 + 1] * rstd * w4.y;
    o.z = v[q * 4 + 2] * rstd * w4.z;
    o.w = v[q * 4 + 3] * rstd * w4.w;
    *(float4*)(yrow + e) = o;
  }
}

extern "C" void kernel_launch(void* const* d_in, const int* in_sizes, int n_in,
                              void* d_out, int out_size, void* d_ws, size_t ws_size,
                              hipStream_t stream) {
  const float* hs      = (const float*)d_in[0];
  const float* W_in    = (const float*)d_in[1];
  const float* conv_w  = (const float*)d_in[2];
  const float* conv_b  = (const float*)d_in[3];
  const float* dt_bias = (const float*)d_in[4];
  const float* A_log   = (const float*)d_in[5];
  const float* D_param = (const float*)d_in[6];
  const float* norm_w  = (const float*)d_in[7];
  const float* W_out   = (const float*)d_in[8];
  float* out = (float*)d_out;

  float* ws   = (float*)d_ws;
  float* zx   = ws;                                      // (B*L, 4240); cols [2048,4096) reused as y_intra
  float* xy   = zx + (size_t)BB * LL * DINPROJ;          // (B*L, 2048): x after conv, y after ssd_out
  float* Bm   = xy + (size_t)BB * LL * DINNER;           // (B*L, 64)
  float* Cm   = Bm + (size_t)BB * LL * NS;               // (B*L, 64)
  float* dtv  = Cm + (size_t)BB * LL * NS;               // (B*L, 16)
  float* clog = dtv + (size_t)BB * LL * NH;              // (B*16, 1024) per-(b,h) within-chunk cumlog
  float* S    = clog + (size_t)BB * LL * NH;             // (B*16*16, 128*64) chunk states / Hprev

  const int M = BB * LL;

  sgemm_nt<<<dim3((DINPROJ + 127) / 128, M / 128), 256, 0, stream>>>(hs, W_in, zx, M, DINPROJ, DMODEL);
  conv_silu<<<(BB * LL * CONVDIM + 255) / 256, 256, 0, stream>>>(zx, conv_w, conv_b, xy, Bm, Cm);
  dt_kernel<<<(BB * LL * NH + 255) / 256, 256, 0, stream>>>(zx, dt_bias, dtv);
  cumlog_kernel<<<2, 256, 0, stream>>>(dtv, A_log, clog);
  ssd_intra<<<BB * NH * NCH, 256, 0, stream>>>(xy, Bm, Cm, dtv, clog, zx, S);
  ssd_scan<<<(BB * NH * HD * NS) / 256, 256, 0, stream>>>(S, clog);
  ssd_out<<<BB * NH * NCH, 256, 0, stream>>>(xy, zx, Cm, clog, S, D_param);
  gate_norm<<<M, 256, 0, stream>>>(xy, zx, norm_w);
  sgemm_nt<<<dim3(DMODEL / 128, M / 128), 256, 0, stream>>>(xy, W_out, out, M, DMODEL, DINNER);
}

// Round 3
// 196.925 us; speedup vs baseline: 10.8303x; 3.2959x over previous
//
#include <hip/hip_runtime.h>
#include <hip/hip_bf16.h>
#include <math.h>

#define BB 2
#define LL 1024
#define DMODEL 1024
#define DINNER 2048
#define NH 16
#define HD 128
#define NS 64
#define CONVDIM 2176
#define DINPROJ 4240
#define QC 64
#define NCH 16

typedef short bf16x8 __attribute__((ext_vector_type(8)));   // 8 bf16 in 4 VGPRs (guide §3)
typedef float f32x4 __attribute__((ext_vector_type(4)));

__device__ __forceinline__ unsigned int bfpair(float lo, float hi) {
  unsigned int a = __float_as_uint(lo); a = (a + 0x7fffu + ((a >> 16) & 1u)) >> 16;
  unsigned int b = __float_as_uint(hi); b = (b + 0x7fffu + ((b >> 16) & 1u)) >> 16;
  return a | (b << 16);
}

// ---- pack fp32 [R][C] row-major -> bf16 tiles of [128 rows][32 k], swizzled LDS image ----
// tile id = tm*(C/32)+tk, 8192 B each. group (r, s) holds logical k-half h = s ^ ((r>>1)&3).
__global__ __launch_bounds__(256) void pack_bf16(const float* __restrict__ src,
                                                 ushort* __restrict__ dst,
                                                 int R, int C, int TM) {
  const int KT = C >> 5;
  const int id = blockIdx.x * 256 + threadIdx.x;
  if (id >= TM * KT * 512) return;
  const int tile = id >> 9;
  const int g = id & 511;
  const int r = g >> 2, s = g & 3;
  const int h = (s ^ (r >> 1)) & 3;
  const int tm = tile / KT, tk = tile - tm * KT;
  const int row = tm * 128 + r;
  const int k = tk * 32 + h * 8;
  uint4 pk = make_uint4(0u, 0u, 0u, 0u);
  if (row < R) {
    const float4 a = *(const float4*)(src + (size_t)row * C + k);
    const float4 b = *(const float4*)(src + (size_t)row * C + k + 4);
    pk.x = bfpair(a.x, a.y); pk.y = bfpair(a.z, a.w);
    pk.z = bfpair(b.x, b.y); pk.w = bfpair(b.z, b.w);
  }
  *(uint4*)(dst + (size_t)id * 8) = pk;
}

// ---- bf16 MFMA GEMM: C[m,n] = sum_k A[m,k]*B[n,k]; A,B pre-packed swizzled tiles ----
__global__ __launch_bounds__(256) void mfma_gemm(const ushort* __restrict__ Ap,
                                                 const ushort* __restrict__ Bp,
                                                 float* __restrict__ C,
                                                 int ldC, int Kt) {
  __shared__ ushort lds[2][2][4096];   // [buf][A/B][8KB tile]
  const int tid = threadIdx.x;
  const int w = tid >> 6, lane = tid & 63;
  const int wr = w >> 1, wc = w & 1;
  const int l15 = lane & 15, lg = lane >> 4;
  const int bm = blockIdx.y * 128, bn = blockIdx.x * 128;
  const ushort* At = Ap + (size_t)blockIdx.y * Kt * 4096;
  const ushort* Bt = Bp + (size_t)blockIdx.x * Kt * 4096;

  int offA[4], offB[4];
#pragma unroll
  for (int i = 0; i < 4; ++i) {
    const int r = wr * 64 + i * 16 + l15;
    offA[i] = r * 64 + (((lg ^ (r >> 1)) & 3) << 4);
    const int c = wc * 64 + i * 16 + l15;
    offB[i] = c * 64 + (((lg ^ (c >> 1)) & 3) << 4);
  }
  f32x4 acc[4][4] = {};

#define STAGE(buf, kt)                                                                   \
  do {                                                                                   \
    const char* ga_ = (const char*)(At + (size_t)(kt) * 4096);                           \
    const char* gb_ = (const char*)(Bt + (size_t)(kt) * 4096);                           \
    char* la_ = (char*)&lds[buf][0][0];                                                  \
    char* lb_ = (char*)&lds[buf][1][0];                                                  \
    _Pragma("unroll")                                                                    \
    for (int q = 0; q < 2; ++q) {                                                        \
      __builtin_amdgcn_global_load_lds(                                                  \
          (const __attribute__((address_space(1))) void*)(ga_ + q * 4096 + tid * 16),    \
          (__attribute__((address_space(3))) void*)(la_ + q * 4096 + (w << 10)), 16, 0, 0); \
      __builtin_amdgcn_global_load_lds(                                                  \
          (const __attribute__((address_space(1))) void*)(gb_ + q * 4096 + tid * 16),    \
          (__attribute__((address_space(3))) void*)(lb_ + q * 4096 + (w << 10)), 16, 0, 0); \
    }                                                                                    \
  } while (0)

  STAGE(0, 0);
  __syncthreads();
  int cur = 0;
  for (int kt = 0; kt < Kt; ++kt) {
    if (kt + 1 < Kt) {
      const int nb = cur ^ 1;
      STAGE(nb, kt + 1);
    }
    bf16x8 af[4], bfr[4];
#pragma unroll
    for (int i = 0; i < 4; ++i) af[i] = *(const bf16x8*)((const char*)&lds[cur][0][0] + offA[i]);
#pragma unroll
    for (int i = 0; i < 4; ++i) bfr[i] = *(const bf16x8*)((const char*)&lds[cur][1][0] + offB[i]);
#pragma unroll
    for (int mi = 0; mi < 4; ++mi)
#pragma unroll
      for (int ni = 0; ni < 4; ++ni)
        acc[mi][ni] = __builtin_amdgcn_mfma_f32_16x16x32_bf16(af[mi], bfr[ni], acc[mi][ni], 0, 0, 0);
    __syncthreads();
    cur ^= 1;
  }
#undef STAGE

#pragma unroll
  for (int mi = 0; mi < 4; ++mi) {
    const int row0 = bm + wr * 64 + mi * 16 + lg * 4;
#pragma unroll
    for (int ni = 0; ni < 4; ++ni) {
      const int col = bn + wc * 64 + ni * 16 + l15;
      float* cp = C + (size_t)row0 * ldC + col;
      cp[0] = acc[mi][ni][0];
      cp[(size_t)ldC] = acc[mi][ni][1];
      cp[(size_t)2 * ldC] = acc[mi][ni][2];
      cp[(size_t)3 * ldC] = acc[mi][ni][3];
    }
  }
}

// ---- fp32 GEMV for the 16 dt columns + softplus ----
__global__ __launch_bounds__(256) void dt_gemv(const float* __restrict__ hs,
                                               const float* __restrict__ W_in,
                                               const float* __restrict__ dt_bias,
                                               float* __restrict__ dtv) {
  __shared__ float hl[1024];
  __shared__ float part[256];
  const int bl = blockIdx.x;
  const int t = threadIdx.x;
  *(float4*)(hl + t * 4) = *(const float4*)(hs + (size_t)bl * 1024 + t * 4);
  __syncthreads();
  const int h = t & 15, ks = t >> 4;
  const float* wrow = W_in + (size_t)(DINNER + CONVDIM + h) * 1024 + ks * 64;
  const float* xs = hl + ks * 64;
  float p = 0.f;
#pragma unroll
  for (int j = 0; j < 64; j += 4) {
    const float4 wv = *(const float4*)(wrow + j);
    const float4 xv = *(const float4*)(xs + j);
    p += wv.x * xv.x + wv.y * xv.y + wv.z * xv.z + wv.w * xv.w;
  }
  part[t] = p;
  __syncthreads();
  if (t < 16) {
    float sum = 0.f;
#pragma unroll
    for (int j = 0; j < 16; ++j) sum += part[t + 16 * j];
    const float x = sum + dt_bias[t];
    dtv[bl * 16 + t] = (x > 20.f) ? x : log1pf(expf(x));
  }
}

// ---- causal depthwise conv(4) + bias + SiLU, with channel split ----
__global__ __launch_bounds__(256) void conv_silu(const float* __restrict__ zx,
                                                 const float* __restrict__ conv_w,
                                                 const float* __restrict__ conv_b,
                                                 float* __restrict__ xy,
                                                 float* __restrict__ Bm,
                                                 float* __restrict__ Cm) {
  const int idx = blockIdx.x * 256 + threadIdx.x;
  if (idx >= BB * LL * CONVDIM) return;
  const int c = idx % CONVDIM;
  const int bl = idx / CONVDIM;
  const int l = bl & (LL - 1);
  const float w0 = conv_w[c * 4 + 0], w1 = conv_w[c * 4 + 1];
  const float w2 = conv_w[c * 4 + 2], w3 = conv_w[c * 4 + 3];
  const float* base = zx + (size_t)bl * DINPROJ + DINNER + c;
  float acc = conv_b[c];
  acc = fmaf(base[0], w3, acc);
  if (l >= 1) acc = fmaf(base[-1 * DINPROJ], w2, acc);
  if (l >= 2) acc = fmaf(base[-2 * DINPROJ], w1, acc);
  if (l >= 3) acc = fmaf(base[-3 * DINPROJ], w0, acc);
  const float s = acc / (1.f + expf(-acc));
  if (c < DINNER)                    xy[(size_t)bl * DINNER + c] = s;
  else if (c < DINNER + NS)          Bm[bl * NS + (c - DINNER)] = s;
  else                               Cm[bl * NS + (c - DINNER - NS)] = s;
}

// ---- within-chunk cumulative log-decay ----
__global__ __launch_bounds__(256) void cumlog_kernel(const float* __restrict__ dtv,
                                                     const float* __restrict__ A_log,
                                                     float* __restrict__ clog) {
  const int idx = blockIdx.x * 256 + threadIdx.x;
  if (idx >= BB * NH * NCH) return;
  const int c = idx & (NCH - 1);
  const int bh = idx >> 4;
  const int b = bh >> 4, h = bh & (NH - 1);
  const float A = -__expf(A_log[h]);
  float run = 0.f;
  for (int i = 0; i < QC; ++i) {
    run += A * dtv[(size_t)(b * LL + c * QC + i) * NH + h];
    clog[(size_t)bh * LL + c * QC + i] = run;
  }
}

// ---- SSD intra-chunk: y_intra and chunk-state S ----
__global__ __launch_bounds__(256) void ssd_intra(const float* __restrict__ xy,
                                                 const float* __restrict__ Bm,
                                                 const float* __restrict__ Cm,
                                                 const float* __restrict__ dtv,
                                                 const float* __restrict__ clog,
                                                 float* __restrict__ zx,
                                                 float* __restrict__ S) {
  __shared__ float sBT[NS][QC];
  __shared__ float sCT[NS][QC];
  __shared__ float sB[QC][NS];
  __shared__ float su[QC][HD];
  __shared__ float sPT[QC][QC];
  __shared__ float scl[QC];
  __shared__ float swend[QC];
  const int blk = blockIdx.x;
  const int bh = blk >> 4, c = blk & (NCH - 1);
  const int b = bh >> 4, h = bh & (NH - 1);
  const int t0 = c * QC;
  const int tid = threadIdx.x;

  const float* Bg = Bm + (size_t)(b * LL + t0) * NS;
  const float* Cg = Cm + (size_t)(b * LL + t0) * NS;
#pragma unroll
  for (int j = 0; j < 4; ++j) {
    const int e = j * 1024 + tid * 4;
    const int r = e >> 6, n = e & 63;
    const float4 bv = *(const float4*)(Bg + e);
    const float4 cv = *(const float4*)(Cg + e);
    sB[r][n] = bv.x; sB[r][n + 1] = bv.y; sB[r][n + 2] = bv.z; sB[r][n + 3] = bv.w;
    sBT[n][r] = bv.x; sBT[n + 1][r] = bv.y; sBT[n + 2][r] = bv.z; sBT[n + 3][r] = bv.w;
    sCT[n][r] = cv.x; sCT[n + 1][r] = cv.y; sCT[n + 2][r] = cv.z; sCT[n + 3][r] = cv.w;
  }
#pragma unroll
  for (int j = 0; j < 8; ++j) {
    const int e = j * 1024 + tid * 4;
    const int s = e >> 7, p = e & 127;
    const float dt = dtv[(size_t)(b * LL + t0 + s) * NH + h];
    const float4 xv = *(const float4*)(xy + (size_t)(b * LL + t0 + s) * DINNER + h * HD + p);
    su[s][p] = dt * xv.x; su[s][p + 1] = dt * xv.y; su[s][p + 2] = dt * xv.z; su[s][p + 3] = dt * xv.w;
  }
  if (tid < QC) scl[tid] = clog[(size_t)bh * LL + t0 + tid];
  __syncthreads();
  if (tid < QC) swend[tid] = __expf(scl[QC - 1] - scl[tid]);

  {
    const int tb = (tid >> 4) * 4;
    const int sb = (tid & 15) * 4;
    float g[4][4] = {};
#pragma unroll 8
    for (int n = 0; n < NS; ++n) {
      const float4 cv = *(const float4*)&sCT[n][tb];
      const float4 bv = *(const float4*)&sBT[n][sb];
      const float cr[4] = {cv.x, cv.y, cv.z, cv.w};
      const float br[4] = {bv.x, bv.y, bv.z, bv.w};
#pragma unroll
      for (int i = 0; i < 4; ++i)
#pragma unroll
        for (int j = 0; j < 4; ++j) g[i][j] = fmaf(cr[i], br[j], g[i][j]);
    }
#pragma unroll
    for (int i = 0; i < 4; ++i) {
      const int t = tb + i;
      const float cl_t = scl[t];
#pragma unroll
      for (int j = 0; j < 4; ++j) {
        const int s = sb + j;
        sPT[s][t] = (s <= t) ? g[i][j] * __expf(cl_t - scl[s]) : 0.f;
      }
    }
  }
  __syncthreads();

  {
    const int tq = (tid >> 4) * 4;
    const int pb = (tid & 15) * 8;
    float acc[4][8] = {};
    for (int s = 0; s < QC; ++s) {
      const float4 w4 = *(const float4*)&sPT[s][tq];
      const float4 u0 = *(const float4*)&su[s][pb];
      const float4 u1 = *(const float4*)&su[s][pb + 4];
      const float wr[4] = {w4.x, w4.y, w4.z, w4.w};
      const float ur[8] = {u0.x, u0.y, u0.z, u0.w, u1.x, u1.y, u1.z, u1.w};
#pragma unroll
      for (int i = 0; i < 4; ++i)
#pragma unroll
        for (int j = 0; j < 8; ++j) acc[i][j] = fmaf(wr[i], ur[j], acc[i][j]);
    }
#pragma unroll
    for (int i = 0; i < 4; ++i) {
      float* yp = zx + (size_t)(b * LL + t0 + tq + i) * DINPROJ + DINNER + h * HD + pb;
      *(float4*)yp       = make_float4(acc[i][0], acc[i][1], acc[i][2], acc[i][3]);
      *(float4*)(yp + 4) = make_float4(acc[i][4], acc[i][5], acc[i][6], acc[i][7]);
    }
  }

  {
    const int p0 = (tid >> 3) * 4;
    const int nb = (tid & 7) * 8;
    float acc[4][8] = {};
    for (int s = 0; s < QC; ++s) {
      const float w = swend[s];
      const float4 uv = *(const float4*)&su[s][p0];
      const float4 b0 = *(const float4*)&sB[s][nb];
      const float4 b1 = *(const float4*)&sB[s][nb + 4];
      const float ur[4] = {uv.x * w, uv.y * w, uv.z * w, uv.w * w};
      const float br[8] = {b0.x, b0.y, b0.z, b0.w, b1.x, b1.y, b1.z, b1.w};
#pragma unroll
      for (int i = 0; i < 4; ++i)
#pragma unroll
        for (int j = 0; j < 8; ++j) acc[i][j] = fmaf(ur[i], br[j], acc[i][j]);
    }
    float* Sg = S + (size_t)blk * (HD * NS);
#pragma unroll
    for (int i = 0; i < 4; ++i) {
      float* sp = Sg + (size_t)(p0 + i) * NS + nb;
      *(float4*)sp       = make_float4(acc[i][0], acc[i][1], acc[i][2], acc[i][3]);
      *(float4*)(sp + 4) = make_float4(acc[i][4], acc[i][5], acc[i][6], acc[i][7]);
    }
  }
}

// ---- inter-chunk scan over chunk states ----
__global__ __launch_bounds__(256) void ssd_scan(float* __restrict__ S,
                                                const float* __restrict__ clog) {
  const int idx = blockIdx.x * 256 + threadIdx.x;
  const int pn = idx & (HD * NS - 1);
  const int bh = idx >> 13;
  float* Sp = S + (size_t)bh * NCH * (HD * NS) + pn;
  const float* cl = clog + (size_t)bh * LL;
  float H = 0.f;
#pragma unroll
  for (int c = 0; c < NCH; ++c) {
    const float dec = __expf(cl[c * QC + QC - 1]);
    const float s = Sp[(size_t)c * (HD * NS)];
    Sp[(size_t)c * (HD * NS)] = H;
    H = dec * H + s;
  }
}

// ---- y = y_intra + exp(cl)*C·Hprev + D*x (in place on xy) ----
__global__ __launch_bounds__(256) void ssd_out(float* __restrict__ xy,
                                               const float* __restrict__ zx,
                                               const float* __restrict__ Cm,
                                               const float* __restrict__ clog,
                                               const float* __restrict__ S,
                                               const float* __restrict__ Dp_) {
  __shared__ float sHT[NS][HD];
  __shared__ float sCT[NS][QC];
  __shared__ float scl[QC];
  const int blk = blockIdx.x;
  const int bh = blk >> 4, c = blk & (NCH - 1);
  const int b = bh >> 4, h = bh & (NH - 1);
  const int t0 = c * QC;
  const int tid = threadIdx.x;
  const float* Hg = S + (size_t)blk * (HD * NS);
#pragma unroll
  for (int j = 0; j < 8; ++j) {
    const int e = j * 1024 + tid * 4;
    const int p = e >> 6, n = e & 63;
    const float4 hv = *(const float4*)(Hg + e);
    sHT[n][p] = hv.x; sHT[n + 1][p] = hv.y; sHT[n + 2][p] = hv.z; sHT[n + 3][p] = hv.w;
  }
  const float* Cg = Cm + (size_t)(b * LL + t0) * NS;
#pragma unroll
  for (int j = 0; j < 4; ++j) {
    const int e = j * 1024 + tid * 4;
    const int r = e >> 6, n = e & 63;
    const float4 cv = *(const float4*)(Cg + e);
    sCT[n][r] = cv.x; sCT[n + 1][r] = cv.y; sCT[n + 2][r] = cv.z; sCT[n + 3][r] = cv.w;
  }
  if (tid < QC) scl[tid] = clog[(size_t)bh * LL + t0 + tid];
  __syncthreads();
  const int tq = (tid >> 4) * 4;
  const int pb = (tid & 15) * 8;
  float acc[4][8] = {};
  for (int n = 0; n < NS; ++n) {
    const float4 cv = *(const float4*)&sCT[n][tq];
    const float4 h0 = *(const float4*)&sHT[n][pb];
    const float4 h1 = *(const float4*)&sHT[n][pb + 4];
    const float cr[4] = {cv.x, cv.y, cv.z, cv.w};
    const float hr[8] = {h0.x, h0.y, h0.z, h0.w, h1.x, h1.y, h1.z, h1.w};
#pragma unroll
    for (int i = 0; i < 4; ++i)
#pragma unroll
      for (int j = 0; j < 8; ++j) acc[i][j] = fmaf(cr[i], hr[j], acc[i][j]);
  }
  const float Dv = Dp_[h];
#pragma unroll
  for (int i = 0; i < 4; ++i) {
    const int t = tq + i;
    const float sc = __expf(scl[t]);
    const size_t row = (size_t)(b * LL + t0 + t);
    const float* yp = zx + row * DINPROJ + DINNER + h * HD + pb;
    float* xp = xy + row * DINNER + h * HD + pb;
    const float4 y0 = *(const float4*)yp, y1 = *(const float4*)(yp + 4);
    const float4 x0 = *(const float4*)xp, x1 = *(const float4*)(xp + 4);
    float4 o0, o1;
    o0.x = y0.x + sc * acc[i][0] + Dv * x0.x;
    o0.y = y0.y + sc * acc[i][1] + Dv * x0.y;
    o0.z = y0.z + sc * acc[i][2] + Dv * x0.z;
    o0.w = y0.w + sc * acc[i][3] + Dv * x0.w;
    o1.x = y1.x + sc * acc[i][4] + Dv * x1.x;
    o1.y = y1.y + sc * acc[i][5] + Dv * x1.y;
    o1.z = y1.z + sc * acc[i][6] + Dv * x1.z;
    o1.w = y1.w + sc * acc[i][7] + Dv * x1.w;
    *(float4*)xp = o0;
    *(float4*)(xp + 4) = o1;
  }
}

// ---- y *= silu(z); RMSNorm; emit packed bf16 tiles for out-proj ----
__global__ __launch_bounds__(256) void gate_norm_pack(const float* __restrict__ xy,
                                                      const float* __restrict__ zx,
                                                      const float* __restrict__ nw,
                                                      ushort* __restrict__ yP) {
  __shared__ float red[4];
  const int m = blockIdx.x;
  const int t = threadIdx.x;
  const float* yrow = xy + (size_t)m * DINNER;
  const float* zrow = zx + (size_t)m * DINPROJ;
  const int e = t * 8;
  const float4 y0 = *(const float4*)(yrow + e), y1 = *(const float4*)(yrow + e + 4);
  const float4 z0 = *(const float4*)(zrow + e), z1 = *(const float4*)(zrow + e + 4);
  float v[8];
  v[0] = y0.x * (z0.x / (1.f + expf(-z0.x)));
  v[1] = y0.y * (z0.y / (1.f + expf(-z0.y)));
  v[2] = y0.z * (z0.z / (1.f + expf(-z0.z)));
  v[3] = y0.w * (z0.w / (1.f + expf(-z0.w)));
  v[4] = y1.x * (z1.x / (1.f + expf(-z1.x)));
  v[5] = y1.y * (z1.y / (1.f + expf(-z1.y)));
  v[6] = y1.z * (z1.z / (1.f + expf(-z1.z)));
  v[7] = y1.w * (z1.w / (1.f + expf(-z1.w)));
  float ss = 0.f;
#pragma unroll
  for (int j = 0; j < 8; ++j) ss += v[j] * v[j];
#pragma unroll
  for (int off = 32; off; off >>= 1) ss += __shfl_down(ss, off);
  const int lane = t & 63, wid = t >> 6;
  if (lane == 0) red[wid] = ss;
  __syncthreads();
  const float tot = red[0] + red[1] + red[2] + red[3];
  const float rstd = rsqrtf(tot * (1.f / DINNER) + 1e-5f);
  const float4 w0 = *(const float4*)(nw + e), w1 = *(const float4*)(nw + e + 4);
  v[0] *= rstd * w0.x; v[1] *= rstd * w0.y; v[2] *= rstd * w0.z; v[3] *= rstd * w0.w;
  v[4] *= rstd * w1.x; v[5] *= rstd * w1.y; v[6] *= rstd * w1.z; v[7] *= rstd * w1.w;
  // packed-tile slot (tile [m>>7][t>>2], row r=m&127, logical half h=t&3)
  const int r = m & 127;
  const int tk = t >> 2;
  const int s = (t ^ (r >> 1)) & 3;
  uint4 pk;
  pk.x = bfpair(v[0], v[1]); pk.y = bfpair(v[2], v[3]);
  pk.z = bfpair(v[4], v[5]); pk.w = bfpair(v[6], v[7]);
  *(uint4*)(yP + (size_t)((m >> 7) * 64 + tk) * 4096 + r * 32 + s * 8) = pk;
}

extern "C" void kernel_launch(void* const* d_in, const int* in_sizes, int n_in,
                              void* d_out, int out_size, void* d_ws, size_t ws_size,
                              hipStream_t stream) {
  const float* hs      = (const float*)d_in[0];
  const float* W_in    = (const float*)d_in[1];
  const float* conv_w  = (const float*)d_in[2];
  const float* conv_b  = (const float*)d_in[3];
  const float* dt_bias = (const float*)d_in[4];
  const float* A_log   = (const float*)d_in[5];
  const float* D_param = (const float*)d_in[6];
  const float* norm_w  = (const float*)d_in[7];
  const float* W_out   = (const float*)d_in[8];
  float* out = (float*)d_out;

  float* ws   = (float*)d_ws;
  float* zx   = ws;                                      // (2048, 4240)
  float* xy   = zx + (size_t)BB * LL * DINPROJ;          // (2048, 2048)
  float* Bm   = xy + (size_t)BB * LL * DINNER;           // (2048, 64)
  float* Cm   = Bm + (size_t)BB * LL * NS;               // (2048, 64)
  float* dtv  = Cm + (size_t)BB * LL * NS;               // (2048, 16)
  float* clog = dtv + (size_t)BB * LL * NH;              // (32, 1024)
  float* S    = clog + (size_t)BB * LL * NH;             // (512, 8192) = 16.8 MB

  // packed bf16 buffers alias S (S is written at ssd_intra, long after in-proj GEMM;
  // yP/WoutP are written after ssd_out, when S is dead).
  ushort* hsP   = (ushort*)S;                 // 2048x1024 bf16  (phase 1)
  ushort* WinP  = (ushort*)S + 2097152;       // 4224x1024 bf16  (phase 1)
  ushort* yP    = (ushort*)S;                 // 2048x2048 bf16  (phase 2)
  ushort* WoutP = (ushort*)S + 4194304;       // 1024x2048 bf16  (phase 2)

  const int M = BB * LL;

  pack_bf16<<<(16 * 32 * 512) / 256, 256, 0, stream>>>(hs, hsP, 2048, 1024, 16);
  pack_bf16<<<(33 * 32 * 512) / 256, 256, 0, stream>>>(W_in, WinP, 4224, 1024, 33);
  dt_gemv<<<M, 256, 0, stream>>>(hs, W_in, dt_bias, dtv);
  mfma_gemm<<<dim3(33, 16), 256, 0, stream>>>(hsP, WinP, zx, DINPROJ, 1024 / 32);
  conv_silu<<<(BB * LL * CONVDIM + 255) / 256, 256, 0, stream>>>(zx, conv_w, conv_b, xy, Bm, Cm);
  cumlog_kernel<<<2, 256, 0, stream>>>(dtv, A_log, clog);
  ssd_intra<<<BB * NH * NCH, 256, 0, stream>>>(xy, Bm, Cm, dtv, clog, zx, S);
  ssd_scan<<<(BB * NH * HD * NS) / 256, 256, 0, stream>>>(S, clog);
  ssd_out<<<BB * NH * NCH, 256, 0, stream>>>(xy, zx, Cm, clog, S, D_param);
  pack_bf16<<<(8 * 64 * 512) / 256, 256, 0, stream>>>(W_out, WoutP, 1024, 2048, 8);
  gate_norm_pack<<<M, 256, 0, stream>>>(xy, zx, norm_w, yP);
  mfma_gemm<<<dim3(8, 16), 256, 0, stream>>>(yP, WoutP, out, DMODEL, 2048 / 32);
}

// Round 4
// 178.403 us; speedup vs baseline: 11.9547x; 1.1038x over previous
//
#include <hip/hip_runtime.h>
#include <hip/hip_bf16.h>
#include <math.h>

#define BB 2
#define LL 1024
#define DMODEL 1024
#define DINNER 2048
#define NH 16
#define HD 128
#define NS 64
#define CONVDIM 2176
#define DINPROJ 4240
#define QC 64
#define NCH 16
#define LSTR 72   // LDS row stride in ushorts (144 B = 64 bf16 + 16B pad) -> conflict-free b128 frag reads

typedef short bf16x8 __attribute__((ext_vector_type(8)));
typedef float f32x4 __attribute__((ext_vector_type(4)));

__device__ __forceinline__ unsigned int bfpair(float lo, float hi) {
  unsigned int a = __float_as_uint(lo); a = (a + 0x7fffu + ((a >> 16) & 1u)) >> 16;
  unsigned int b = __float_as_uint(hi); b = (b + 0x7fffu + ((b >> 16) & 1u)) >> 16;
  return a | (b << 16);
}
__device__ __forceinline__ ushort bf1(float f) {
  unsigned int u = __float_as_uint(f);
  return (ushort)((u + 0x7fffu + ((u >> 16) & 1u)) >> 16);
}
__device__ __forceinline__ uint4 pack8(const float* v) {
  return make_uint4(bfpair(v[0], v[1]), bfpair(v[2], v[3]), bfpair(v[4], v[5]), bfpair(v[6], v[7]));
}

// ---- pack fp32 [R][C] row-major -> bf16 tiles of [128 rows][32 k], swizzled LDS image ----
__global__ __launch_bounds__(256) void pack_bf16(const float* __restrict__ src,
                                                 ushort* __restrict__ dst,
                                                 int R, int C, int TM) {
  const int KT = C >> 5;
  const int id = blockIdx.x * 256 + threadIdx.x;
  if (id >= TM * KT * 512) return;
  const int tile = id >> 9;
  const int g = id & 511;
  const int r = g >> 2, s = g & 3;
  const int h = (s ^ (r >> 1)) & 3;
  const int tm = tile / KT, tk = tile - tm * KT;
  const int row = tm * 128 + r;
  const int k = tk * 32 + h * 8;
  uint4 pk = make_uint4(0u, 0u, 0u, 0u);
  if (row < R) {
    const float4 a = *(const float4*)(src + (size_t)row * C + k);
    const float4 b = *(const float4*)(src + (size_t)row * C + k + 4);
    pk.x = bfpair(a.x, a.y); pk.y = bfpair(a.z, a.w);
    pk.z = bfpair(b.x, b.y); pk.w = bfpair(b.z, b.w);
  }
  *(uint4*)(dst + (size_t)id * 8) = pk;
}

// ---- bf16 MFMA GEMM: C[m,n] = sum_k A[m,k]*B[n,k]; A,B pre-packed swizzled tiles ----
__global__ __launch_bounds__(256) void mfma_gemm(const ushort* __restrict__ Ap,
                                                 const ushort* __restrict__ Bp,
                                                 float* __restrict__ C,
                                                 int ldC, int Kt) {
  __shared__ ushort lds[2][2][4096];
  const int tid = threadIdx.x;
  const int w = tid >> 6, lane = tid & 63;
  const int wr = w >> 1, wc = w & 1;
  const int l15 = lane & 15, lg = lane >> 4;
  const int bm = blockIdx.y * 128, bn = blockIdx.x * 128;
  const ushort* At = Ap + (size_t)blockIdx.y * Kt * 4096;
  const ushort* Bt = Bp + (size_t)blockIdx.x * Kt * 4096;

  int offA[4], offB[4];
#pragma unroll
  for (int i = 0; i < 4; ++i) {
    const int r = wr * 64 + i * 16 + l15;
    offA[i] = r * 64 + (((lg ^ (r >> 1)) & 3) << 4);
    const int c = wc * 64 + i * 16 + l15;
    offB[i] = c * 64 + (((lg ^ (c >> 1)) & 3) << 4);
  }
  f32x4 acc[4][4] = {};

#define STAGE(buf, kt)                                                                   \
  do {                                                                                   \
    const char* ga_ = (const char*)(At + (size_t)(kt) * 4096);                           \
    const char* gb_ = (const char*)(Bt + (size_t)(kt) * 4096);                           \
    char* la_ = (char*)&lds[buf][0][0];                                                  \
    char* lb_ = (char*)&lds[buf][1][0];                                                  \
    _Pragma("unroll")                                                                    \
    for (int q = 0; q < 2; ++q) {                                                        \
      __builtin_amdgcn_global_load_lds(                                                  \
          (const __attribute__((address_space(1))) void*)(ga_ + q * 4096 + tid * 16),    \
          (__attribute__((address_space(3))) void*)(la_ + q * 4096 + (w << 10)), 16, 0, 0); \
      __builtin_amdgcn_global_load_lds(                                                  \
          (const __attribute__((address_space(1))) void*)(gb_ + q * 4096 + tid * 16),    \
          (__attribute__((address_space(3))) void*)(lb_ + q * 4096 + (w << 10)), 16, 0, 0); \
    }                                                                                    \
  } while (0)

  STAGE(0, 0);
  __syncthreads();
  int cur = 0;
  for (int kt = 0; kt < Kt; ++kt) {
    if (kt + 1 < Kt) {
      const int nb = cur ^ 1;
      STAGE(nb, kt + 1);
    }
    bf16x8 af[4], bfr[4];
#pragma unroll
    for (int i = 0; i < 4; ++i) af[i] = *(const bf16x8*)((const char*)&lds[cur][0][0] + offA[i]);
#pragma unroll
    for (int i = 0; i < 4; ++i) bfr[i] = *(const bf16x8*)((const char*)&lds[cur][1][0] + offB[i]);
#pragma unroll
    for (int mi = 0; mi < 4; ++mi)
#pragma unroll
      for (int ni = 0; ni < 4; ++ni)
        acc[mi][ni] = __builtin_amdgcn_mfma_f32_16x16x32_bf16(af[mi], bfr[ni], acc[mi][ni], 0, 0, 0);
    __syncthreads();
    cur ^= 1;
  }
#undef STAGE

#pragma unroll
  for (int mi = 0; mi < 4; ++mi) {
    const int row0 = bm + wr * 64 + mi * 16 + lg * 4;
#pragma unroll
    for (int ni = 0; ni < 4; ++ni) {
      const int col = bn + wc * 64 + ni * 16 + l15;
      float* cp = C + (size_t)row0 * ldC + col;
      cp[0] = acc[mi][ni][0];
      cp[(size_t)ldC] = acc[mi][ni][1];
      cp[(size_t)2 * ldC] = acc[mi][ni][2];
      cp[(size_t)3 * ldC] = acc[mi][ni][3];
    }
  }
}

// ---- fp32 GEMV for the 16 dt columns + softplus ----
__global__ __launch_bounds__(256) void dt_gemv(const float* __restrict__ hs,
                                               const float* __restrict__ W_in,
                                               const float* __restrict__ dt_bias,
                                               float* __restrict__ dtv) {
  __shared__ float hl[1024];
  __shared__ float part[256];
  const int bl = blockIdx.x;
  const int t = threadIdx.x;
  *(float4*)(hl + t * 4) = *(const float4*)(hs + (size_t)bl * 1024 + t * 4);
  __syncthreads();
  const int h = t & 15, ks = t >> 4;
  const float* wrow = W_in + (size_t)(DINNER + CONVDIM + h) * 1024 + ks * 64;
  const float* xs = hl + ks * 64;
  float p = 0.f;
#pragma unroll
  for (int j = 0; j < 64; j += 4) {
    const float4 wv = *(const float4*)(wrow + j);
    const float4 xv = *(const float4*)(xs + j);
    p += wv.x * xv.x + wv.y * xv.y + wv.z * xv.z + wv.w * xv.w;
  }
  part[t] = p;
  __syncthreads();
  if (t < 16) {
    float sum = 0.f;
#pragma unroll
    for (int j = 0; j < 16; ++j) sum += part[t + 16 * j];
    const float x = sum + dt_bias[t];
    dtv[bl * 16 + t] = (x > 20.f) ? x : log1pf(expf(x));
  }
}

// ---- causal depthwise conv(4) + bias + SiLU, with channel split ----
__global__ __launch_bounds__(256) void conv_silu(const float* __restrict__ zx,
                                                 const float* __restrict__ conv_w,
                                                 const float* __restrict__ conv_b,
                                                 float* __restrict__ xy,
                                                 float* __restrict__ Bm,
                                                 float* __restrict__ Cm) {
  const int idx = blockIdx.x * 256 + threadIdx.x;
  if (idx >= BB * LL * CONVDIM) return;
  const int c = idx % CONVDIM;
  const int bl = idx / CONVDIM;
  const int l = bl & (LL - 1);
  const float w0 = conv_w[c * 4 + 0], w1 = conv_w[c * 4 + 1];
  const float w2 = conv_w[c * 4 + 2], w3 = conv_w[c * 4 + 3];
  const float* base = zx + (size_t)bl * DINPROJ + DINNER + c;
  float acc = conv_b[c];
  acc = fmaf(base[0], w3, acc);
  if (l >= 1) acc = fmaf(base[-1 * DINPROJ], w2, acc);
  if (l >= 2) acc = fmaf(base[-2 * DINPROJ], w1, acc);
  if (l >= 3) acc = fmaf(base[-3 * DINPROJ], w0, acc);
  const float s = acc / (1.f + expf(-acc));
  if (c < DINNER)                    xy[(size_t)bl * DINNER + c] = s;
  else if (c < DINNER + NS)          Bm[bl * NS + (c - DINNER)] = s;
  else                               Cm[bl * NS + (c - DINNER - NS)] = s;
}

// ---- within-chunk cumulative log-decay ----
__global__ __launch_bounds__(256) void cumlog_kernel(const float* __restrict__ dtv,
                                                     const float* __restrict__ A_log,
                                                     float* __restrict__ clog) {
  const int idx = blockIdx.x * 256 + threadIdx.x;
  if (idx >= BB * NH * NCH) return;
  const int c = idx & (NCH - 1);
  const int bh = idx >> 4;
  const int b = bh >> 4, h = bh & (NH - 1);
  const float A = -__expf(A_log[h]);
  float run = 0.f;
  for (int i = 0; i < QC; ++i) {
    run += A * dtv[(size_t)(b * LL + c * QC + i) * NH + h];
    clog[(size_t)bh * LL + c * QC + i] = run;
  }
}

// ---- SSD intra-chunk via bf16 MFMA: y_intra and chunk-state S ----
// G = C.B^T (64x64,K=64) -> P = mask*decay*dt (.) G -> Y = P.X (64x128,K=64), S = X^T.(w dt B) (128x64,K=64)
__global__ __launch_bounds__(256) void ssd_intra(const float* __restrict__ xy,
                                                 const float* __restrict__ Bm,
                                                 const float* __restrict__ Cm,
                                                 const float* __restrict__ dtv,
                                                 const float* __restrict__ clog,
                                                 float* __restrict__ zx,
                                                 float* __restrict__ S) {
  __shared__ __align__(16) ushort sC[64 * LSTR];    // rows t, k=n
  __shared__ __align__(16) ushort sB[64 * LSTR];    // rows s, k=n
  __shared__ __align__(16) ushort sBT[64 * LSTR];   // rows n, k=s, val = w_s*dt_s*B[s][n]
  __shared__ __align__(16) ushort sXT[128 * LSTR];  // rows p, k=s, val = x[s][p]
  __shared__ __align__(16) ushort sP[64 * LSTR];    // rows t, k=s, val = dt_s*mask*decay*G
  __shared__ float scl[QC], sdt[QC], swdt[QC];
  const int blk = blockIdx.x;
  const int bh = blk >> 4, c = blk & (NCH - 1);
  const int b = bh >> 4, h = bh & (NH - 1);
  const int t0 = c * QC;
  const int tid = threadIdx.x;
  const int w = tid >> 6, lane = tid & 63, l15 = lane & 15, lg = lane >> 4;

  if (tid < QC) {
    const float cl = clog[(size_t)bh * LL + t0 + tid];
    const float clend = clog[(size_t)bh * LL + t0 + QC - 1];
    const float dt = dtv[(size_t)(b * LL + t0 + tid) * NH + h];
    scl[tid] = cl; sdt[tid] = dt;
    swdt[tid] = __expf(clend - cl) * dt;
  }
  __syncthreads();

  const float* Bg = Bm + (size_t)(b * LL + t0) * NS;
  const float* Cg = Cm + (size_t)(b * LL + t0) * NS;
#pragma unroll
  for (int j = 0; j < 4; ++j) {
    const int f = j * 256 + tid;
    const int r = f >> 4, c4 = f & 15;
    const float4 bv = *(const float4*)(Bg + r * NS + c4 * 4);
    const float4 cv = *(const float4*)(Cg + r * NS + c4 * 4);
    *(uint2*)(sB + r * LSTR + c4 * 4) = make_uint2(bfpair(bv.x, bv.y), bfpair(bv.z, bv.w));
    *(uint2*)(sC + r * LSTR + c4 * 4) = make_uint2(bfpair(cv.x, cv.y), bfpair(cv.z, cv.w));
  }
  {  // B^T weighted, coalesced column-strip reads
    const int n = tid & 63, sg = tid >> 6;
    float bw[16];
#pragma unroll
    for (int j = 0; j < 16; ++j) {
      const int s = sg * 16 + j;
      bw[j] = swdt[s] * Bg[(size_t)s * NS + n];
    }
    *(uint4*)(sBT + n * LSTR + sg * 16) = pack8(bw);
    *(uint4*)(sBT + n * LSTR + sg * 16 + 8) = pack8(bw + 8);
  }
  {  // X^T, coalesced column-strip reads
    const int p = tid & 127, sh = tid >> 7;
    const float* xg = xy + (size_t)(b * LL + t0 + sh * 32) * DINNER + h * HD + p;
    float xv[32];
#pragma unroll
    for (int j = 0; j < 32; ++j) xv[j] = xg[(size_t)j * DINNER];
#pragma unroll
    for (int q = 0; q < 4; ++q)
      *(uint4*)(sXT + p * LSTR + sh * 32 + q * 8) = pack8(xv + q * 8);
  }
  __syncthreads();

  // matmul 1: G[t][s] (each wave: one 16-row t-strip)
  f32x4 g[4] = {};
#pragma unroll
  for (int ks = 0; ks < 2; ++ks) {
    const bf16x8 ca = *(const bf16x8*)((const char*)sC + (w * 16 + l15) * 144 + ks * 64 + lg * 16);
#pragma unroll
    for (int ni = 0; ni < 4; ++ni) {
      const bf16x8 bb = *(const bf16x8*)((const char*)sB + (ni * 16 + l15) * 144 + ks * 64 + lg * 16);
      g[ni] = __builtin_amdgcn_mfma_f32_16x16x32_bf16(ca, bb, g[ni], 0, 0, 0);
    }
  }
  // mask / decay / dt-fold -> sP (bf16)
#pragma unroll
  for (int ni = 0; ni < 4; ++ni) {
    const int s = ni * 16 + l15;
    const float cls = scl[s], dts = sdt[s];
#pragma unroll
    for (int j = 0; j < 4; ++j) {
      const int t = w * 16 + lg * 4 + j;
      const float v = (s <= t) ? g[ni][j] * __expf(scl[t] - cls) * dts : 0.f;
      sP[t * LSTR + s] = bf1(v);
    }
  }
  // matmul 3: S[p][n] (each wave: 32 p-rows) — scheduled before the barrier to hide it
  f32x4 sa[2][4] = {};
#pragma unroll
  for (int ks = 0; ks < 2; ++ks) {
    const bf16x8 a0 = *(const bf16x8*)((const char*)sXT + (w * 32 + l15) * 144 + ks * 64 + lg * 16);
    const bf16x8 a1 = *(const bf16x8*)((const char*)sXT + (w * 32 + 16 + l15) * 144 + ks * 64 + lg * 16);
#pragma unroll
    for (int nj = 0; nj < 4; ++nj) {
      const bf16x8 bb = *(const bf16x8*)((const char*)sBT + (nj * 16 + l15) * 144 + ks * 64 + lg * 16);
      sa[0][nj] = __builtin_amdgcn_mfma_f32_16x16x32_bf16(a0, bb, sa[0][nj], 0, 0, 0);
      sa[1][nj] = __builtin_amdgcn_mfma_f32_16x16x32_bf16(a1, bb, sa[1][nj], 0, 0, 0);
    }
  }
  float* Sg = S + (size_t)blk * (HD * NS);
#pragma unroll
  for (int mi = 0; mi < 2; ++mi)
#pragma unroll
    for (int nj = 0; nj < 4; ++nj)
#pragma unroll
      for (int j = 0; j < 4; ++j)
        Sg[(size_t)(w * 32 + mi * 16 + lg * 4 + j) * NS + nj * 16 + l15] = sa[mi][nj][j];
  __syncthreads();

  // matmul 2: Y[t][p] = sum_s P'[t][s] * X[s][p]
  f32x4 y[8] = {};
#pragma unroll
  for (int ks = 0; ks < 2; ++ks) {
    const bf16x8 pa = *(const bf16x8*)((const char*)sP + (w * 16 + l15) * 144 + ks * 64 + lg * 16);
#pragma unroll
    for (int ni = 0; ni < 8; ++ni) {
      const bf16x8 xb = *(const bf16x8*)((const char*)sXT + (ni * 16 + l15) * 144 + ks * 64 + lg * 16);
      y[ni] = __builtin_amdgcn_mfma_f32_16x16x32_bf16(pa, xb, y[ni], 0, 0, 0);
    }
  }
  float* yg = zx + (size_t)(b * LL + t0) * DINPROJ + DINNER + h * HD;
#pragma unroll
  for (int ni = 0; ni < 8; ++ni)
#pragma unroll
    for (int j = 0; j < 4; ++j)
      yg[(size_t)(w * 16 + lg * 4 + j) * DINPROJ + ni * 16 + l15] = y[ni][j];
}

// ---- inter-chunk scan over chunk states ----
__global__ __launch_bounds__(256) void ssd_scan(float* __restrict__ S,
                                                const float* __restrict__ clog) {
  const int idx = blockIdx.x * 256 + threadIdx.x;
  const int pn = idx & (HD * NS - 1);
  const int bh = idx >> 13;
  float* Sp = S + (size_t)bh * NCH * (HD * NS) + pn;
  const float* cl = clog + (size_t)bh * LL;
  float H = 0.f;
#pragma unroll
  for (int c = 0; c < NCH; ++c) {
    const float dec = __expf(cl[c * QC + QC - 1]);
    const float s = Sp[(size_t)c * (HD * NS)];
    Sp[(size_t)c * (HD * NS)] = H;
    H = dec * H + s;
  }
}

// ---- y = y_intra + exp(cl)*C.H^T + D*x (bf16 MFMA, in place on xy) ----
__global__ __launch_bounds__(256) void ssd_out(float* __restrict__ xy,
                                               const float* __restrict__ zx,
                                               const float* __restrict__ Cm,
                                               const float* __restrict__ clog,
                                               const float* __restrict__ S,
                                               const float* __restrict__ Dp_) {
  __shared__ __align__(16) ushort sC[64 * LSTR];    // rows t, k=n
  __shared__ __align__(16) ushort sH[128 * LSTR];   // rows p, k=n
  __shared__ float sE[QC];
  const int blk = blockIdx.x;
  const int bh = blk >> 4, c = blk & (NCH - 1);
  const int b = bh >> 4, h = bh & (NH - 1);
  const int t0 = c * QC;
  const int tid = threadIdx.x;
  const int w = tid >> 6, lane = tid & 63, l15 = lane & 15, lg = lane >> 4;

  if (tid < QC) sE[tid] = __expf(clog[(size_t)bh * LL + t0 + tid]);
  const float* Cg = Cm + (size_t)(b * LL + t0) * NS;
#pragma unroll
  for (int j = 0; j < 4; ++j) {
    const int f = j * 256 + tid, r = f >> 4, c4 = f & 15;
    const float4 cv = *(const float4*)(Cg + r * NS + c4 * 4);
    *(uint2*)(sC + r * LSTR + c4 * 4) = make_uint2(bfpair(cv.x, cv.y), bfpair(cv.z, cv.w));
  }
  const float* Hg = S + (size_t)blk * (HD * NS);
#pragma unroll
  for (int j = 0; j < 8; ++j) {
    const int f = j * 256 + tid, p = f >> 4, n4 = f & 15;
    const float4 hv = *(const float4*)(Hg + (size_t)p * NS + n4 * 4);
    *(uint2*)(sH + p * LSTR + n4 * 4) = make_uint2(bfpair(hv.x, hv.y), bfpair(hv.z, hv.w));
  }
  __syncthreads();

  f32x4 y2[8] = {};
#pragma unroll
  for (int ks = 0; ks < 2; ++ks) {
    const bf16x8 ca = *(const bf16x8*)((const char*)sC + (w * 16 + l15) * 144 + ks * 64 + lg * 16);
#pragma unroll
    for (int ni = 0; ni < 8; ++ni) {
      const bf16x8 hb = *(const bf16x8*)((const char*)sH + (ni * 16 + l15) * 144 + ks * 64 + lg * 16);
      y2[ni] = __builtin_amdgcn_mfma_f32_16x16x32_bf16(ca, hb, y2[ni], 0, 0, 0);
    }
  }
  const float Dv = Dp_[h];
#pragma unroll
  for (int ni = 0; ni < 8; ++ni) {
    const int p = ni * 16 + l15;
#pragma unroll
    for (int j = 0; j < 4; ++j) {
      const int t = w * 16 + lg * 4 + j;
      const size_t row = (size_t)(b * LL + t0 + t);
      const float yi = zx[row * DINPROJ + DINNER + h * HD + p];
      float* xp = xy + row * DINNER + h * HD + p;
      *xp = yi + sE[t] * y2[ni][j] + Dv * (*xp);
    }
  }
}

// ---- y *= silu(z); RMSNorm; emit packed bf16 tiles for out-proj ----
__global__ __launch_bounds__(256) void gate_norm_pack(const float* __restrict__ xy,
                                                      const float* __restrict__ zx,
                                                      const float* __restrict__ nw,
                                                      ushort* __restrict__ yP) {
  __shared__ float red[4];
  const int m = blockIdx.x;
  const int t = threadIdx.x;
  const float* yrow = xy + (size_t)m * DINNER;
  const float* zrow = zx + (size_t)m * DINPROJ;
  const int e = t * 8;
  const float4 y0 = *(const float4*)(yrow + e), y1 = *(const float4*)(yrow + e + 4);
  const float4 z0 = *(const float4*)(zrow + e), z1 = *(const float4*)(zrow + e + 4);
  float v[8];
  v[0] = y0.x * (z0.x / (1.f + expf(-z0.x)));
  v[1] = y0.y * (z0.y / (1.f + expf(-z0.y)));
  v[2] = y0.z * (z0.z / (1.f + expf(-z0.z)));
  v[3] = y0.w * (z0.w / (1.f + expf(-z0.w)));
  v[4] = y1.x * (z1.x / (1.f + expf(-z1.x)));
  v[5] = y1.y * (z1.y / (1.f + expf(-z1.y)));
  v[6] = y1.z * (z1.z / (1.f + expf(-z1.z)));
  v[7] = y1.w * (z1.w / (1.f + expf(-z1.w)));
  float ss = 0.f;
#pragma unroll
  for (int j = 0; j < 8; ++j) ss += v[j] * v[j];
#pragma unroll
  for (int off = 32; off; off >>= 1) ss += __shfl_down(ss, off);
  const int lane = t & 63, wid = t >> 6;
  if (lane == 0) red[wid] = ss;
  __syncthreads();
  const float tot = red[0] + red[1] + red[2] + red[3];
  const float rstd = rsqrtf(tot * (1.f / DINNER) + 1e-5f);
  const float4 w0 = *(const float4*)(nw + e), w1 = *(const float4*)(nw + e + 4);
  v[0] *= rstd * w0.x; v[1] *= rstd * w0.y; v[2] *= rstd * w0.z; v[3] *= rstd * w0.w;
  v[4] *= rstd * w1.x; v[5] *= rstd * w1.y; v[6] *= rstd * w1.z; v[7] *= rstd * w1.w;
  const int r = m & 127;
  const int tk = t >> 2;
  const int s = (t ^ (r >> 1)) & 3;
  uint4 pk;
  pk.x = bfpair(v[0], v[1]); pk.y = bfpair(v[2], v[3]);
  pk.z = bfpair(v[4], v[5]); pk.w = bfpair(v[6], v[7]);
  *(uint4*)(yP + (size_t)((m >> 7) * 64 + tk) * 4096 + r * 32 + s * 8) = pk;
}

extern "C" void kernel_launch(void* const* d_in, const int* in_sizes, int n_in,
                              void* d_out, int out_size, void* d_ws, size_t ws_size,
                              hipStream_t stream) {
  const float* hs      = (const float*)d_in[0];
  const float* W_in    = (const float*)d_in[1];
  const float* conv_w  = (const float*)d_in[2];
  const float* conv_b  = (const float*)d_in[3];
  const float* dt_bias = (const float*)d_in[4];
  const float* A_log   = (const float*)d_in[5];
  const float* D_param = (const float*)d_in[6];
  const float* norm_w  = (const float*)d_in[7];
  const float* W_out   = (const float*)d_in[8];
  float* out = (float*)d_out;

  float* ws   = (float*)d_ws;
  float* zx   = ws;                                      // (2048, 4240)
  float* xy   = zx + (size_t)BB * LL * DINPROJ;          // (2048, 2048)
  float* Bm   = xy + (size_t)BB * LL * DINNER;           // (2048, 64)
  float* Cm   = Bm + (size_t)BB * LL * NS;               // (2048, 64)
  float* dtv  = Cm + (size_t)BB * LL * NS;               // (2048, 16)
  float* clog = dtv + (size_t)BB * LL * NH;              // (32, 1024)
  float* S    = clog + (size_t)BB * LL * NH;             // (512, 8192)

  ushort* hsP   = (ushort*)S;                 // 2048x1024 bf16  (phase 1)
  ushort* WinP  = (ushort*)S + 2097152;       // 4224x1024 bf16  (phase 1)
  ushort* yP    = (ushort*)S;                 // 2048x2048 bf16  (phase 2)
  ushort* WoutP = (ushort*)S + 4194304;       // 1024x2048 bf16  (phase 2)

  const int M = BB * LL;

  pack_bf16<<<(16 * 32 * 512) / 256, 256, 0, stream>>>(hs, hsP, 2048, 1024, 16);
  pack_bf16<<<(33 * 32 * 512) / 256, 256, 0, stream>>>(W_in, WinP, 4224, 1024, 33);
  dt_gemv<<<M, 256, 0, stream>>>(hs, W_in, dt_bias, dtv);
  mfma_gemm<<<dim3(33, 16), 256, 0, stream>>>(hsP, WinP, zx, DINPROJ, 1024 / 32);
  conv_silu<<<(BB * LL * CONVDIM + 255) / 256, 256, 0, stream>>>(zx, conv_w, conv_b, xy, Bm, Cm);
  cumlog_kernel<<<2, 256, 0, stream>>>(dtv, A_log, clog);
  ssd_intra<<<BB * NH * NCH, 256, 0, stream>>>(xy, Bm, Cm, dtv, clog, zx, S);
  ssd_scan<<<(BB * NH * HD * NS) / 256, 256, 0, stream>>>(S, clog);
  ssd_out<<<BB * NH * NCH, 256, 0, stream>>>(xy, zx, Cm, clog, S, D_param);
  pack_bf16<<<(8 * 64 * 512) / 256, 256, 0, stream>>>(W_out, WoutP, 1024, 2048, 8);
  gate_norm_pack<<<M, 256, 0, stream>>>(xy, zx, norm_w, yP);
  mfma_gemm<<<dim3(8, 16), 256, 0, stream>>>(yP, WoutP, out, DMODEL, 2048 / 32);
}

// Round 5
// 172.142 us; speedup vs baseline: 12.3895x; 1.0364x over previous
//
#include <hip/hip_runtime.h>
#include <hip/hip_bf16.h>
#include <math.h>

#define BB 2
#define LL 1024
#define DMODEL 1024
#define DINNER 2048
#define NH 16
#define HD 128
#define NS 64
#define CONVDIM 2176
#define DINPROJ 4240
#define QC 64
#define NCH 16
#define LSTR 72   // LDS row stride in ushorts (144 B) -> conflict-free b128 frag reads

typedef short bf16x8 __attribute__((ext_vector_type(8)));
typedef float f32x4 __attribute__((ext_vector_type(4)));

__device__ __forceinline__ unsigned int bfpair(float lo, float hi) {
  unsigned int a = __float_as_uint(lo); a = (a + 0x7fffu + ((a >> 16) & 1u)) >> 16;
  unsigned int b = __float_as_uint(hi); b = (b + 0x7fffu + ((b >> 16) & 1u)) >> 16;
  return a | (b << 16);
}
__device__ __forceinline__ ushort bf1(float f) {
  unsigned int u = __float_as_uint(f);
  return (ushort)((u + 0x7fffu + ((u >> 16) & 1u)) >> 16);
}
__device__ __forceinline__ uint4 pack8(const float* v) {
  return make_uint4(bfpair(v[0], v[1]), bfpair(v[2], v[3]), bfpair(v[4], v[5]), bfpair(v[6], v[7]));
}

// ---- pack helper: fp32 [R][C] row-major -> bf16 tiles [TR rows][32 k], swizzled LDS image ----
__device__ __forceinline__ void pack_tiles(const float* __restrict__ src,
                                           ushort* __restrict__ dst,
                                           int id, int C, int TR) {
  const int KT = C >> 5;
  const int per_tile = TR * 4;                   // uint4 slots per tile
  const int tile = id / per_tile;
  const int g = id - tile * per_tile;
  const int r = g >> 2, s = g & 3;
  const int h = (s ^ (r >> 1)) & 3;
  const int tm = tile / KT, tk = tile - tm * KT;
  const int row = tm * TR + r;
  const int k = tk * 32 + h * 8;
  const float4 a = *(const float4*)(src + (size_t)row * C + k);
  const float4 b = *(const float4*)(src + (size_t)row * C + k + 4);
  uint4 pk;
  pk.x = bfpair(a.x, a.y); pk.y = bfpair(a.z, a.w);
  pk.z = bfpair(b.x, b.y); pk.w = bfpair(b.z, b.w);
  *(uint4*)(dst + (size_t)id * 8) = pk;
}

// ---- phase-1 prep: pack hs, W_in, W_out + dt GEMV, branched on blockIdx ----
#define PREP_HS 1024
#define PREP_WIN 2112
#define PREP_WOUT 1024
__global__ __launch_bounds__(256) void prep_kernel(const float* __restrict__ hs,
                                                   const float* __restrict__ W_in,
                                                   const float* __restrict__ W_out,
                                                   const float* __restrict__ dt_bias,
                                                   ushort* __restrict__ hsP,
                                                   ushort* __restrict__ WinP,
                                                   ushort* __restrict__ WoutP,
                                                   float* __restrict__ dtv) {
  __shared__ float hl[1024];
  __shared__ float part[256];
  const int blk = blockIdx.x;
  const int t = threadIdx.x;
  if (blk < PREP_HS) {                       // hs: 2048x1024, 128-row tiles
    pack_tiles(hs, hsP, blk * 256 + t, 1024, 128);
  } else if (blk < PREP_HS + PREP_WIN) {     // W_in rows 0..4223: 128-row tiles
    pack_tiles(W_in, WinP, (blk - PREP_HS) * 256 + t, 1024, 128);
  } else if (blk < PREP_HS + PREP_WIN + PREP_WOUT) {  // W_out: 1024x2048, 128-row tiles
    pack_tiles(W_out, WoutP, (blk - PREP_HS - PREP_WIN) * 256 + t, 2048, 128);
  } else {                                   // dt GEMV + softplus (fp32 exact)
    const int bl = blk - (PREP_HS + PREP_WIN + PREP_WOUT);
    *(float4*)(hl + t * 4) = *(const float4*)(hs + (size_t)bl * 1024 + t * 4);
    __syncthreads();
    const int h = t & 15, ks = t >> 4;
    const float* wrow = W_in + (size_t)(DINNER + CONVDIM + h) * 1024 + ks * 64;
    const float* xs = hl + ks * 64;
    float p = 0.f;
#pragma unroll
    for (int j = 0; j < 64; j += 4) {
      const float4 wv = *(const float4*)(wrow + j);
      const float4 xv = *(const float4*)(xs + j);
      p += wv.x * xv.x + wv.y * xv.y + wv.z * xv.z + wv.w * xv.w;
    }
    part[t] = p;
    __syncthreads();
    if (t < 16) {
      float sum = 0.f;
#pragma unroll
      for (int j = 0; j < 16; ++j) sum += part[t + 16 * j];
      const float x = sum + dt_bias[t];
      dtv[bl * 16 + t] = (x > 20.f) ? x : log1pf(expf(x));
    }
  }
}

// ---- bf16 MFMA GEMM, 128x128 tile: C[m,n] = sum_k A[m,k]*B[n,k] ----
__global__ __launch_bounds__(256) void mfma_gemm(const ushort* __restrict__ Ap,
                                                 const ushort* __restrict__ Bp,
                                                 float* __restrict__ C,
                                                 int ldC, int Kt) {
  __shared__ ushort lds[2][2][4096];
  const int tid = threadIdx.x;
  const int w = tid >> 6, lane = tid & 63;
  const int wr = w >> 1, wc = w & 1;
  const int l15 = lane & 15, lg = lane >> 4;
  const int bm = blockIdx.y * 128, bn = blockIdx.x * 128;
  const ushort* At = Ap + (size_t)blockIdx.y * Kt * 4096;
  const ushort* Bt = Bp + (size_t)blockIdx.x * Kt * 4096;

  int offA[4], offB[4];
#pragma unroll
  for (int i = 0; i < 4; ++i) {
    const int r = wr * 64 + i * 16 + l15;
    offA[i] = r * 64 + (((lg ^ (r >> 1)) & 3) << 4);
    const int c = wc * 64 + i * 16 + l15;
    offB[i] = c * 64 + (((lg ^ (c >> 1)) & 3) << 4);
  }
  f32x4 acc[4][4] = {};

#define STAGE(buf, kt)                                                                   \
  do {                                                                                   \
    const char* ga_ = (const char*)(At + (size_t)(kt) * 4096);                           \
    const char* gb_ = (const char*)(Bt + (size_t)(kt) * 4096);                           \
    char* la_ = (char*)&lds[buf][0][0];                                                  \
    char* lb_ = (char*)&lds[buf][1][0];                                                  \
    _Pragma("unroll")                                                                    \
    for (int q = 0; q < 2; ++q) {                                                        \
      __builtin_amdgcn_global_load_lds(                                                  \
          (const __attribute__((address_space(1))) void*)(ga_ + q * 4096 + tid * 16),    \
          (__attribute__((address_space(3))) void*)(la_ + q * 4096 + (w << 10)), 16, 0, 0); \
      __builtin_amdgcn_global_load_lds(                                                  \
          (const __attribute__((address_space(1))) void*)(gb_ + q * 4096 + tid * 16),    \
          (__attribute__((address_space(3))) void*)(lb_ + q * 4096 + (w << 10)), 16, 0, 0); \
    }                                                                                    \
  } while (0)

  STAGE(0, 0);
  __syncthreads();
  int cur = 0;
  for (int kt = 0; kt < Kt; ++kt) {
    if (kt + 1 < Kt) STAGE(cur ^ 1, kt + 1);
    bf16x8 af[4], bfr[4];
#pragma unroll
    for (int i = 0; i < 4; ++i) af[i] = *(const bf16x8*)((const char*)&lds[cur][0][0] + offA[i]);
#pragma unroll
    for (int i = 0; i < 4; ++i) bfr[i] = *(const bf16x8*)((const char*)&lds[cur][1][0] + offB[i]);
#pragma unroll
    for (int mi = 0; mi < 4; ++mi)
#pragma unroll
      for (int ni = 0; ni < 4; ++ni)
        acc[mi][ni] = __builtin_amdgcn_mfma_f32_16x16x32_bf16(af[mi], bfr[ni], acc[mi][ni], 0, 0, 0);
    __syncthreads();
    cur ^= 1;
  }
#undef STAGE

#pragma unroll
  for (int mi = 0; mi < 4; ++mi) {
    const int row0 = bm + wr * 64 + mi * 16 + lg * 4;
#pragma unroll
    for (int ni = 0; ni < 4; ++ni) {
      const int col = bn + wc * 64 + ni * 16 + l15;
      float* cp = C + (size_t)row0 * ldC + col;
      cp[0] = acc[mi][ni][0];
      cp[(size_t)ldC] = acc[mi][ni][1];
      cp[(size_t)2 * ldC] = acc[mi][ni][2];
      cp[(size_t)3 * ldC] = acc[mi][ni][3];
    }
  }
}

// ---- out-proj GEMM, 64x128 tile (256 blocks -> all CUs): A = yP 64-row tiles, B = WoutP 128-row tiles
__global__ __launch_bounds__(256) void gemm_out64(const ushort* __restrict__ Ap,
                                                  const ushort* __restrict__ Bp,
                                                  float* __restrict__ C,
                                                  int ldC, int Kt) {
  __shared__ ushort ldsA[2][2048];   // 4 KB tile
  __shared__ ushort ldsB[2][4096];   // 8 KB tile
  const int tid = threadIdx.x;
  const int w = tid >> 6, lane = tid & 63;
  const int l15 = lane & 15, lg = lane >> 4;
  const int bm = blockIdx.y * 64, bn = blockIdx.x * 128;
  const ushort* At = Ap + (size_t)blockIdx.y * Kt * 2048;
  const ushort* Bt = Bp + (size_t)blockIdx.x * Kt * 4096;

  const int ra = w * 16 + l15;
  const int offA = ra * 64 + (((lg ^ (ra >> 1)) & 3) << 4);
  int offB[8];
#pragma unroll
  for (int i = 0; i < 8; ++i) {
    const int c = i * 16 + l15;
    offB[i] = c * 64 + (((lg ^ (c >> 1)) & 3) << 4);
  }
  f32x4 acc[8] = {};

#define STAGE2(buf, kt)                                                                  \
  do {                                                                                   \
    const char* ga_ = (const char*)(At + (size_t)(kt) * 2048);                           \
    const char* gb_ = (const char*)(Bt + (size_t)(kt) * 4096);                           \
    char* la_ = (char*)&ldsA[buf][0];                                                    \
    char* lb_ = (char*)&ldsB[buf][0];                                                    \
    __builtin_amdgcn_global_load_lds(                                                    \
        (const __attribute__((address_space(1))) void*)(ga_ + tid * 16),                 \
        (__attribute__((address_space(3))) void*)(la_ + (w << 10)), 16, 0, 0);           \
    _Pragma("unroll")                                                                    \
    for (int q = 0; q < 2; ++q) {                                                        \
      __builtin_amdgcn_global_load_lds(                                                  \
          (const __attribute__((address_space(1))) void*)(gb_ + q * 4096 + tid * 16),    \
          (__attribute__((address_space(3))) void*)(lb_ + q * 4096 + (w << 10)), 16, 0, 0); \
    }                                                                                    \
  } while (0)

  STAGE2(0, 0);
  __syncthreads();
  int cur = 0;
  for (int kt = 0; kt < Kt; ++kt) {
    if (kt + 1 < Kt) STAGE2(cur ^ 1, kt + 1);
    const bf16x8 af = *(const bf16x8*)((const char*)&ldsA[cur][0] + offA);
    bf16x8 bfr[8];
#pragma unroll
    for (int i = 0; i < 8; ++i) bfr[i] = *(const bf16x8*)((const char*)&ldsB[cur][0] + offB[i]);
#pragma unroll
    for (int ni = 0; ni < 8; ++ni)
      acc[ni] = __builtin_amdgcn_mfma_f32_16x16x32_bf16(af, bfr[ni], acc[ni], 0, 0, 0);
    __syncthreads();
    cur ^= 1;
  }
#undef STAGE2

  const int row0 = bm + w * 16 + lg * 4;
#pragma unroll
  for (int ni = 0; ni < 8; ++ni) {
    const int col = bn + ni * 16 + l15;
    float* cp = C + (size_t)row0 * ldC + col;
    cp[0] = acc[ni][0];
    cp[(size_t)ldC] = acc[ni][1];
    cp[(size_t)2 * ldC] = acc[ni][2];
    cp[(size_t)3 * ldC] = acc[ni][3];
  }
}

// ---- causal depthwise conv(4)+SiLU (+ merged cumlog tail blocks) ----
#define CONV_BLKS ((BB * LL * CONVDIM + 255) / 256)
__global__ __launch_bounds__(256) void conv_cumlog(const float* __restrict__ zx,
                                                   const float* __restrict__ conv_w,
                                                   const float* __restrict__ conv_b,
                                                   float* __restrict__ xy,
                                                   float* __restrict__ Bm,
                                                   float* __restrict__ Cm,
                                                   const float* __restrict__ dtv,
                                                   const float* __restrict__ A_log,
                                                   float* __restrict__ clog) {
  const int blk = blockIdx.x;
  if (blk >= CONV_BLKS) {  // cumlog: 512 lanes over 2 blocks
    const int idx = (blk - CONV_BLKS) * 256 + threadIdx.x;
    if (idx >= BB * NH * NCH) return;
    const int c = idx & (NCH - 1);
    const int bh = idx >> 4;
    const int b = bh >> 4, h = bh & (NH - 1);
    const float A = -__expf(A_log[h]);
    float run = 0.f;
    for (int i = 0; i < QC; ++i) {
      run += A * dtv[(size_t)(b * LL + c * QC + i) * NH + h];
      clog[(size_t)bh * LL + c * QC + i] = run;
    }
    return;
  }
  const int idx = blk * 256 + threadIdx.x;
  const int c = idx % CONVDIM;
  const int bl = idx / CONVDIM;
  const int l = bl & (LL - 1);
  const float w0 = conv_w[c * 4 + 0], w1 = conv_w[c * 4 + 1];
  const float w2 = conv_w[c * 4 + 2], w3 = conv_w[c * 4 + 3];
  const float* base = zx + (size_t)bl * DINPROJ + DINNER + c;
  float acc = conv_b[c];
  acc = fmaf(base[0], w3, acc);
  if (l >= 1) acc = fmaf(base[-1 * DINPROJ], w2, acc);
  if (l >= 2) acc = fmaf(base[-2 * DINPROJ], w1, acc);
  if (l >= 3) acc = fmaf(base[-3 * DINPROJ], w0, acc);
  const float s = acc / (1.f + expf(-acc));
  if (c < DINNER)                    xy[(size_t)bl * DINNER + c] = s;
  else if (c < DINNER + NS)          Bm[bl * NS + (c - DINNER)] = s;
  else                               Cm[bl * NS + (c - DINNER - NS)] = s;
}

// ---- SSD intra-chunk via bf16 MFMA ----
__global__ __launch_bounds__(256) void ssd_intra(const float* __restrict__ xy,
                                                 const float* __restrict__ Bm,
                                                 const float* __restrict__ Cm,
                                                 const float* __restrict__ dtv,
                                                 const float* __restrict__ clog,
                                                 float* __restrict__ zx,
                                                 float* __restrict__ S) {
  __shared__ __align__(16) ushort sC[64 * LSTR];
  __shared__ __align__(16) ushort sB[64 * LSTR];
  __shared__ __align__(16) ushort sBT[64 * LSTR];
  __shared__ __align__(16) ushort sXT[128 * LSTR];
  __shared__ __align__(16) ushort sP[64 * LSTR];
  __shared__ float scl[QC], sdt[QC], swdt[QC];
  const int blk = blockIdx.x;
  const int bh = blk >> 4, c = blk & (NCH - 1);
  const int b = bh >> 4, h = bh & (NH - 1);
  const int t0 = c * QC;
  const int tid = threadIdx.x;
  const int w = tid >> 6, lane = tid & 63, l15 = lane & 15, lg = lane >> 4;

  if (tid < QC) {
    const float cl = clog[(size_t)bh * LL + t0 + tid];
    const float clend = clog[(size_t)bh * LL + t0 + QC - 1];
    const float dt = dtv[(size_t)(b * LL + t0 + tid) * NH + h];
    scl[tid] = cl; sdt[tid] = dt;
    swdt[tid] = __expf(clend - cl) * dt;
  }
  __syncthreads();

  const float* Bg = Bm + (size_t)(b * LL + t0) * NS;
  const float* Cg = Cm + (size_t)(b * LL + t0) * NS;
#pragma unroll
  for (int j = 0; j < 4; ++j) {
    const int f = j * 256 + tid;
    const int r = f >> 4, c4 = f & 15;
    const float4 bv = *(const float4*)(Bg + r * NS + c4 * 4);
    const float4 cv = *(const float4*)(Cg + r * NS + c4 * 4);
    *(uint2*)(sB + r * LSTR + c4 * 4) = make_uint2(bfpair(bv.x, bv.y), bfpair(bv.z, bv.w));
    *(uint2*)(sC + r * LSTR + c4 * 4) = make_uint2(bfpair(cv.x, cv.y), bfpair(cv.z, cv.w));
  }
  {
    const int n = tid & 63, sg = tid >> 6;
    float bw[16];
#pragma unroll
    for (int j = 0; j < 16; ++j) {
      const int s = sg * 16 + j;
      bw[j] = swdt[s] * Bg[(size_t)s * NS + n];
    }
    *(uint4*)(sBT + n * LSTR + sg * 16) = pack8(bw);
    *(uint4*)(sBT + n * LSTR + sg * 16 + 8) = pack8(bw + 8);
  }
  {
    const int p = tid & 127, sh = tid >> 7;
    const float* xg = xy + (size_t)(b * LL + t0 + sh * 32) * DINNER + h * HD + p;
    float xv[32];
#pragma unroll
    for (int j = 0; j < 32; ++j) xv[j] = xg[(size_t)j * DINNER];
#pragma unroll
    for (int q = 0; q < 4; ++q)
      *(uint4*)(sXT + p * LSTR + sh * 32 + q * 8) = pack8(xv + q * 8);
  }
  __syncthreads();

  f32x4 g[4] = {};
#pragma unroll
  for (int ks = 0; ks < 2; ++ks) {
    const bf16x8 ca = *(const bf16x8*)((const char*)sC + (w * 16 + l15) * 144 + ks * 64 + lg * 16);
#pragma unroll
    for (int ni = 0; ni < 4; ++ni) {
      const bf16x8 bb = *(const bf16x8*)((const char*)sB + (ni * 16 + l15) * 144 + ks * 64 + lg * 16);
      g[ni] = __builtin_amdgcn_mfma_f32_16x16x32_bf16(ca, bb, g[ni], 0, 0, 0);
    }
  }
#pragma unroll
  for (int ni = 0; ni < 4; ++ni) {
    const int s = ni * 16 + l15;
    const float cls = scl[s], dts = sdt[s];
#pragma unroll
    for (int j = 0; j < 4; ++j) {
      const int t = w * 16 + lg * 4 + j;
      const float v = (s <= t) ? g[ni][j] * __expf(scl[t] - cls) * dts : 0.f;
      sP[t * LSTR + s] = bf1(v);
    }
  }
  f32x4 sa[2][4] = {};
#pragma unroll
  for (int ks = 0; ks < 2; ++ks) {
    const bf16x8 a0 = *(const bf16x8*)((const char*)sXT + (w * 32 + l15) * 144 + ks * 64 + lg * 16);
    const bf16x8 a1 = *(const bf16x8*)((const char*)sXT + (w * 32 + 16 + l15) * 144 + ks * 64 + lg * 16);
#pragma unroll
    for (int nj = 0; nj < 4; ++nj) {
      const bf16x8 bb = *(const bf16x8*)((const char*)sBT + (nj * 16 + l15) * 144 + ks * 64 + lg * 16);
      sa[0][nj] = __builtin_amdgcn_mfma_f32_16x16x32_bf16(a0, bb, sa[0][nj], 0, 0, 0);
      sa[1][nj] = __builtin_amdgcn_mfma_f32_16x16x32_bf16(a1, bb, sa[1][nj], 0, 0, 0);
    }
  }
  float* Sg = S + (size_t)blk * (HD * NS);
#pragma unroll
  for (int mi = 0; mi < 2; ++mi)
#pragma unroll
    for (int nj = 0; nj < 4; ++nj)
#pragma unroll
      for (int j = 0; j < 4; ++j)
        Sg[(size_t)(w * 32 + mi * 16 + lg * 4 + j) * NS + nj * 16 + l15] = sa[mi][nj][j];
  __syncthreads();

  f32x4 y[8] = {};
#pragma unroll
  for (int ks = 0; ks < 2; ++ks) {
    const bf16x8 pa = *(const bf16x8*)((const char*)sP + (w * 16 + l15) * 144 + ks * 64 + lg * 16);
#pragma unroll
    for (int ni = 0; ni < 8; ++ni) {
      const bf16x8 xb = *(const bf16x8*)((const char*)sXT + (ni * 16 + l15) * 144 + ks * 64 + lg * 16);
      y[ni] = __builtin_amdgcn_mfma_f32_16x16x32_bf16(pa, xb, y[ni], 0, 0, 0);
    }
  }
  float* yg = zx + (size_t)(b * LL + t0) * DINPROJ + DINNER + h * HD;
#pragma unroll
  for (int ni = 0; ni < 8; ++ni)
#pragma unroll
    for (int j = 0; j < 4; ++j)
      yg[(size_t)(w * 16 + lg * 4 + j) * DINPROJ + ni * 16 + l15] = y[ni][j];
}

// ---- inter-chunk scan over chunk states ----
__global__ __launch_bounds__(256) void ssd_scan(float* __restrict__ S,
                                                const float* __restrict__ clog) {
  const int idx = blockIdx.x * 256 + threadIdx.x;
  const int pn = idx & (HD * NS - 1);
  const int bh = idx >> 13;
  float* Sp = S + (size_t)bh * NCH * (HD * NS) + pn;
  const float* cl = clog + (size_t)bh * LL;
  float H = 0.f;
#pragma unroll
  for (int c = 0; c < NCH; ++c) {
    const float dec = __expf(cl[c * QC + QC - 1]);
    const float s = Sp[(size_t)c * (HD * NS)];
    Sp[(size_t)c * (HD * NS)] = H;
    H = dec * H + s;
  }
}

// ---- y = y_intra + exp(cl)*C.H^T + D*x (bf16 MFMA, in place on xy) ----
__global__ __launch_bounds__(256) void ssd_out(float* __restrict__ xy,
                                               const float* __restrict__ zx,
                                               const float* __restrict__ Cm,
                                               const float* __restrict__ clog,
                                               const float* __restrict__ S,
                                               const float* __restrict__ Dp_) {
  __shared__ __align__(16) ushort sC[64 * LSTR];
  __shared__ __align__(16) ushort sH[128 * LSTR];
  __shared__ float sE[QC];
  const int blk = blockIdx.x;
  const int bh = blk >> 4, c = blk & (NCH - 1);
  const int b = bh >> 4, h = bh & (NH - 1);
  const int t0 = c * QC;
  const int tid = threadIdx.x;
  const int w = tid >> 6, lane = tid & 63, l15 = lane & 15, lg = lane >> 4;

  if (tid < QC) sE[tid] = __expf(clog[(size_t)bh * LL + t0 + tid]);
  const float* Cg = Cm + (size_t)(b * LL + t0) * NS;
#pragma unroll
  for (int j = 0; j < 4; ++j) {
    const int f = j * 256 + tid, r = f >> 4, c4 = f & 15;
    const float4 cv = *(const float4*)(Cg + r * NS + c4 * 4);
    *(uint2*)(sC + r * LSTR + c4 * 4) = make_uint2(bfpair(cv.x, cv.y), bfpair(cv.z, cv.w));
  }
  const float* Hg = S + (size_t)blk * (HD * NS);
#pragma unroll
  for (int j = 0; j < 8; ++j) {
    const int f = j * 256 + tid, p = f >> 4, n4 = f & 15;
    const float4 hv = *(const float4*)(Hg + (size_t)p * NS + n4 * 4);
    *(uint2*)(sH + p * LSTR + n4 * 4) = make_uint2(bfpair(hv.x, hv.y), bfpair(hv.z, hv.w));
  }
  __syncthreads();

  f32x4 y2[8] = {};
#pragma unroll
  for (int ks = 0; ks < 2; ++ks) {
    const bf16x8 ca = *(const bf16x8*)((const char*)sC + (w * 16 + l15) * 144 + ks * 64 + lg * 16);
#pragma unroll
    for (int ni = 0; ni < 8; ++ni) {
      const bf16x8 hb = *(const bf16x8*)((const char*)sH + (ni * 16 + l15) * 144 + ks * 64 + lg * 16);
      y2[ni] = __builtin_amdgcn_mfma_f32_16x16x32_bf16(ca, hb, y2[ni], 0, 0, 0);
    }
  }
  const float Dv = Dp_[h];
#pragma unroll
  for (int ni = 0; ni < 8; ++ni) {
    const int p = ni * 16 + l15;
#pragma unroll
    for (int j = 0; j < 4; ++j) {
      const int t = w * 16 + lg * 4 + j;
      const size_t row = (size_t)(b * LL + t0 + t);
      const float yi = zx[row * DINPROJ + DINNER + h * HD + p];
      float* xp = xy + row * DINNER + h * HD + p;
      *xp = yi + sE[t] * y2[ni][j] + Dv * (*xp);
    }
  }
}

// ---- y *= silu(z); RMSNorm; emit packed bf16 64-row tiles (+ merged W_out no-op removed) ----
__global__ __launch_bounds__(256) void gate_norm_pack(const float* __restrict__ xy,
                                                      const float* __restrict__ zx,
                                                      const float* __restrict__ nw,
                                                      ushort* __restrict__ yP) {
  __shared__ float red[4];
  const int m = blockIdx.x;
  const int t = threadIdx.x;
  const float* yrow = xy + (size_t)m * DINNER;
  const float* zrow = zx + (size_t)m * DINPROJ;
  const int e = t * 8;
  const float4 y0 = *(const float4*)(yrow + e), y1 = *(const float4*)(yrow + e + 4);
  const float4 z0 = *(const float4*)(zrow + e), z1 = *(const float4*)(zrow + e + 4);
  float v[8];
  v[0] = y0.x * (z0.x / (1.f + expf(-z0.x)));
  v[1] = y0.y * (z0.y / (1.f + expf(-z0.y)));
  v[2] = y0.z * (z0.z / (1.f + expf(-z0.z)));
  v[3] = y0.w * (z0.w / (1.f + expf(-z0.w)));
  v[4] = y1.x * (z1.x / (1.f + expf(-z1.x)));
  v[5] = y1.y * (z1.y / (1.f + expf(-z1.y)));
  v[6] = y1.z * (z1.z / (1.f + expf(-z1.z)));
  v[7] = y1.w * (z1.w / (1.f + expf(-z1.w)));
  float ss = 0.f;
#pragma unroll
  for (int j = 0; j < 8; ++j) ss += v[j] * v[j];
#pragma unroll
  for (int off = 32; off; off >>= 1) ss += __shfl_down(ss, off);
  const int lane = t & 63, wid = t >> 6;
  if (lane == 0) red[wid] = ss;
  __syncthreads();
  const float tot = red[0] + red[1] + red[2] + red[3];
  const float rstd = rsqrtf(tot * (1.f / DINNER) + 1e-5f);
  const float4 w0 = *(const float4*)(nw + e), w1 = *(const float4*)(nw + e + 4);
  v[0] *= rstd * w0.x; v[1] *= rstd * w0.y; v[2] *= rstd * w0.z; v[3] *= rstd * w0.w;
  v[4] *= rstd * w1.x; v[5] *= rstd * w1.y; v[6] *= rstd * w1.z; v[7] *= rstd * w1.w;
  // 64-row tile pack: tile (m>>6, t>>2), row r=m&63, half h=t&3, slot s=(h^(r>>1))&3
  const int r = m & 63;
  const int tk = t >> 2;
  const int s = (t ^ (r >> 1)) & 3;
  uint4 pk;
  pk.x = bfpair(v[0], v[1]); pk.y = bfpair(v[2], v[3]);
  pk.z = bfpair(v[4], v[5]); pk.w = bfpair(v[6], v[7]);
  *(uint4*)(yP + (size_t)((m >> 6) * 64 + tk) * 2048 + r * 32 + s * 8) = pk;
}

extern "C" void kernel_launch(void* const* d_in, const int* in_sizes, int n_in,
                              void* d_out, int out_size, void* d_ws, size_t ws_size,
                              hipStream_t stream) {
  const float* hs      = (const float*)d_in[0];
  const float* W_in    = (const float*)d_in[1];
  const float* conv_w  = (const float*)d_in[2];
  const float* conv_b  = (const float*)d_in[3];
  const float* dt_bias = (const float*)d_in[4];
  const float* A_log   = (const float*)d_in[5];
  const float* D_param = (const float*)d_in[6];
  const float* norm_w  = (const float*)d_in[7];
  const float* W_out   = (const float*)d_in[8];
  float* out = (float*)d_out;

  float* ws   = (float*)d_ws;
  float* zx   = ws;                                      // (2048, 4240) 34.7 MB
  float* xy   = zx + (size_t)BB * LL * DINPROJ;          // (2048, 2048) 16.8 MB
  float* Bm   = xy + (size_t)BB * LL * DINNER;           // (2048, 64)
  float* Cm   = Bm + (size_t)BB * LL * NS;               // (2048, 64)
  float* dtv  = Cm + (size_t)BB * LL * NS;               // (2048, 16)
  float* clog = dtv + (size_t)BB * LL * NH;              // (32, 1024)
  float* S    = clog + (size_t)BB * LL * NH;             // (512, 8192) 16.8 MB
  // dedicated bf16 buffers (ws_size ~256 MB per harness fill; total use ~95 MB)
  ushort* hsP   = (ushort*)(S + (size_t)512 * 8192);     // 2048x1024
  ushort* WinP  = hsP + (size_t)2048 * 1024;             // 4224x1024
  ushort* WoutP = WinP + (size_t)4224 * 1024;            // 1024x2048
  ushort* yP    = WoutP + (size_t)1024 * 2048;           // 2048x2048 (64-row tiles)

  const int M = BB * LL;

  prep_kernel<<<PREP_HS + PREP_WIN + PREP_WOUT + M, 256, 0, stream>>>(
      hs, W_in, W_out, dt_bias, hsP, WinP, WoutP, dtv);
  mfma_gemm<<<dim3(33, 16), 256, 0, stream>>>(hsP, WinP, zx, DINPROJ, 1024 / 32);
  conv_cumlog<<<CONV_BLKS + 2, 256, 0, stream>>>(zx, conv_w, conv_b, xy, Bm, Cm, dtv, A_log, clog);
  ssd_intra<<<BB * NH * NCH, 256, 0, stream>>>(xy, Bm, Cm, dtv, clog, zx, S);
  ssd_scan<<<(BB * NH * HD * NS) / 256, 256, 0, stream>>>(S, clog);
  ssd_out<<<BB * NH * NCH, 256, 0, stream>>>(xy, zx, Cm, clog, S, D_param);
  gate_norm_pack<<<M, 256, 0, stream>>>(xy, zx, norm_w, yP);
  gemm_out64<<<dim3(8, 32), 256, 0, stream>>>(yP, WoutP, out, DMODEL, 2048 / 32);
}

// Round 6
// 157.471 us; speedup vs baseline: 13.5438x; 1.0932x over previous
//
#include <hip/hip_runtime.h>
#include <hip/hip_bf16.h>
#include <math.h>

#define BB 2
#define LL 1024
#define DMODEL 1024
#define DINNER 2048
#define NH 16
#define HD 128
#define NS 64
#define CONVDIM 2176
#define DINPROJ 4240
#define QC 64
#define NCH 16
#define LSTR 72   // LDS row stride in ushorts (144 B) -> conflict-free b128 frag reads

typedef short bf16x8 __attribute__((ext_vector_type(8)));
typedef float f32x4 __attribute__((ext_vector_type(4)));

__device__ __forceinline__ unsigned int bfpair(float lo, float hi) {
  unsigned int a = __float_as_uint(lo); a = (a + 0x7fffu + ((a >> 16) & 1u)) >> 16;
  unsigned int b = __float_as_uint(hi); b = (b + 0x7fffu + ((b >> 16) & 1u)) >> 16;
  return a | (b << 16);
}
__device__ __forceinline__ ushort bf1(float f) {
  unsigned int u = __float_as_uint(f);
  return (ushort)((u + 0x7fffu + ((u >> 16) & 1u)) >> 16);
}
__device__ __forceinline__ uint4 pack8(const float* v) {
  return make_uint4(bfpair(v[0], v[1]), bfpair(v[2], v[3]), bfpair(v[4], v[5]), bfpair(v[6], v[7]));
}

// ---- pack helper: fp32 [R][C] row-major -> bf16 tiles [128 rows][32 k], swizzled LDS image ----
__device__ __forceinline__ void pack_tiles(const float* __restrict__ src,
                                           ushort* __restrict__ dst,
                                           int id, int C) {
  const int KT = C >> 5;
  const int tile = id >> 9;
  const int g = id & 511;
  const int r = g >> 2, s = g & 3;
  const int h = (s ^ (r >> 1)) & 3;
  const int tm = tile / KT, tk = tile - tm * KT;
  const int row = tm * 128 + r;
  const int k = tk * 32 + h * 8;
  const float4 a = *(const float4*)(src + (size_t)row * C + k);
  const float4 b = *(const float4*)(src + (size_t)row * C + k + 4);
  uint4 pk;
  pk.x = bfpair(a.x, a.y); pk.y = bfpair(a.z, a.w);
  pk.z = bfpair(b.x, b.y); pk.w = bfpair(b.z, b.w);
  *(uint4*)(dst + (size_t)id * 8) = pk;
}

// ---- phase-1 prep: pack hs, W_in, W_out + dt GEMV, branched on blockIdx ----
#define PREP_HS 1024
#define PREP_WIN 2112
#define PREP_WOUT 1024
__global__ __launch_bounds__(256) void prep_kernel(const float* __restrict__ hs,
                                                   const float* __restrict__ W_in,
                                                   const float* __restrict__ W_out,
                                                   const float* __restrict__ dt_bias,
                                                   ushort* __restrict__ hsP,
                                                   ushort* __restrict__ WinP,
                                                   ushort* __restrict__ WoutP,
                                                   float* __restrict__ dtv) {
  __shared__ float hl[1024];
  __shared__ float part[256];
  const int blk = blockIdx.x;
  const int t = threadIdx.x;
  if (blk < PREP_HS) {
    pack_tiles(hs, hsP, blk * 256 + t, 1024);
  } else if (blk < PREP_HS + PREP_WIN) {
    pack_tiles(W_in, WinP, (blk - PREP_HS) * 256 + t, 1024);
  } else if (blk < PREP_HS + PREP_WIN + PREP_WOUT) {
    pack_tiles(W_out, WoutP, (blk - PREP_HS - PREP_WIN) * 256 + t, 2048);
  } else {
    const int bl = blk - (PREP_HS + PREP_WIN + PREP_WOUT);
    *(float4*)(hl + t * 4) = *(const float4*)(hs + (size_t)bl * 1024 + t * 4);
    __syncthreads();
    const int h = t & 15, ks = t >> 4;
    const float* wrow = W_in + (size_t)(DINNER + CONVDIM + h) * 1024 + ks * 64;
    const float* xs = hl + ks * 64;
    float p = 0.f;
#pragma unroll
    for (int j = 0; j < 64; j += 4) {
      const float4 wv = *(const float4*)(wrow + j);
      const float4 xv = *(const float4*)(xs + j);
      p += wv.x * xv.x + wv.y * xv.y + wv.z * xv.z + wv.w * xv.w;
    }
    part[t] = p;
    __syncthreads();
    if (t < 16) {
      float sum = 0.f;
#pragma unroll
      for (int j = 0; j < 16; ++j) sum += part[t + 16 * j];
      const float x = sum + dt_bias[t];
      dtv[bl * 16 + t] = (x > 20.f) ? x : log1pf(expf(x));
    }
  }
}

// ---- bf16 MFMA GEMM, 128x128 tile, optional split-K via blockIdx.z ----
// C[m,n] (+)= sum_{k in segment z} A[m,k]*B[n,k]; partial z written to C + z*partStride
__global__ __launch_bounds__(256) void mfma_gemm(const ushort* __restrict__ Ap,
                                                 const ushort* __restrict__ Bp,
                                                 float* __restrict__ C,
                                                 int ldC, int KtTot, int Ktl,
                                                 size_t partStride) {
  __shared__ ushort lds[2][2][4096];
  const int tid = threadIdx.x;
  const int w = tid >> 6, lane = tid & 63;
  const int wr = w >> 1, wc = w & 1;
  const int l15 = lane & 15, lg = lane >> 4;
  const int bm = blockIdx.y * 128, bn = blockIdx.x * 128;
  const int kt0 = blockIdx.z * Ktl;
  const ushort* At = Ap + (size_t)blockIdx.y * KtTot * 4096 + (size_t)kt0 * 4096;
  const ushort* Bt = Bp + (size_t)blockIdx.x * KtTot * 4096 + (size_t)kt0 * 4096;
  float* Cz = C + (size_t)blockIdx.z * partStride;

  int offA[4], offB[4];
#pragma unroll
  for (int i = 0; i < 4; ++i) {
    const int r = wr * 64 + i * 16 + l15;
    offA[i] = r * 64 + (((lg ^ (r >> 1)) & 3) << 4);
    const int c = wc * 64 + i * 16 + l15;
    offB[i] = c * 64 + (((lg ^ (c >> 1)) & 3) << 4);
  }
  f32x4 acc[4][4] = {};

#define STAGE(buf, kt)                                                                   \
  do {                                                                                   \
    const char* ga_ = (const char*)(At + (size_t)(kt) * 4096);                           \
    const char* gb_ = (const char*)(Bt + (size_t)(kt) * 4096);                           \
    char* la_ = (char*)&lds[buf][0][0];                                                  \
    char* lb_ = (char*)&lds[buf][1][0];                                                  \
    _Pragma("unroll")                                                                    \
    for (int q = 0; q < 2; ++q) {                                                        \
      __builtin_amdgcn_global_load_lds(                                                  \
          (const __attribute__((address_space(1))) void*)(ga_ + q * 4096 + tid * 16),    \
          (__attribute__((address_space(3))) void*)(la_ + q * 4096 + (w << 10)), 16, 0, 0); \
      __builtin_amdgcn_global_load_lds(                                                  \
          (const __attribute__((address_space(1))) void*)(gb_ + q * 4096 + tid * 16),    \
          (__attribute__((address_space(3))) void*)(lb_ + q * 4096 + (w << 10)), 16, 0, 0); \
    }                                                                                    \
  } while (0)

  STAGE(0, 0);
  __syncthreads();
  int cur = 0;
  for (int kt = 0; kt < Ktl; ++kt) {
    if (kt + 1 < Ktl) STAGE(cur ^ 1, kt + 1);
    bf16x8 af[4], bfr[4];
#pragma unroll
    for (int i = 0; i < 4; ++i) af[i] = *(const bf16x8*)((const char*)&lds[cur][0][0] + offA[i]);
#pragma unroll
    for (int i = 0; i < 4; ++i) bfr[i] = *(const bf16x8*)((const char*)&lds[cur][1][0] + offB[i]);
#pragma unroll
    for (int mi = 0; mi < 4; ++mi)
#pragma unroll
      for (int ni = 0; ni < 4; ++ni)
        acc[mi][ni] = __builtin_amdgcn_mfma_f32_16x16x32_bf16(af[mi], bfr[ni], acc[mi][ni], 0, 0, 0);
    __syncthreads();
    cur ^= 1;
  }
#undef STAGE

#pragma unroll
  for (int mi = 0; mi < 4; ++mi) {
    const int row0 = bm + wr * 64 + mi * 16 + lg * 4;
#pragma unroll
    for (int ni = 0; ni < 4; ++ni) {
      const int col = bn + wc * 64 + ni * 16 + l15;
      float* cp = Cz + (size_t)row0 * ldC + col;
      cp[0] = acc[mi][ni][0];
      cp[(size_t)ldC] = acc[mi][ni][1];
      cp[(size_t)2 * ldC] = acc[mi][ni][2];
      cp[(size_t)3 * ldC] = acc[mi][ni][3];
    }
  }
}

// ---- sum 4 split-K partials -> out ----
__global__ __launch_bounds__(256) void reduce4(const float* __restrict__ P,
                                               float* __restrict__ out) {
  const size_t i = ((size_t)blockIdx.x * 256 + threadIdx.x) * 4;
  const size_t st = (size_t)DMODEL * BB * LL;
  float4 a = *(const float4*)(P + i);
  const float4 b = *(const float4*)(P + st + i);
  const float4 c = *(const float4*)(P + 2 * st + i);
  const float4 d = *(const float4*)(P + 3 * st + i);
  a.x += b.x + c.x + d.x;
  a.y += b.y + c.y + d.y;
  a.z += b.z + c.z + d.z;
  a.w += b.w + c.w + d.w;
  *(float4*)(out + i) = a;
}

// ---- causal depthwise conv(4)+SiLU (+ merged cumlog tail blocks) ----
#define CONV_BLKS ((BB * LL * CONVDIM + 255) / 256)
__global__ __launch_bounds__(256) void conv_cumlog(const float* __restrict__ zx,
                                                   const float* __restrict__ conv_w,
                                                   const float* __restrict__ conv_b,
                                                   float* __restrict__ xy,
                                                   float* __restrict__ Bm,
                                                   float* __restrict__ Cm,
                                                   const float* __restrict__ dtv,
                                                   const float* __restrict__ A_log,
                                                   float* __restrict__ clog) {
  const int blk = blockIdx.x;
  if (blk >= CONV_BLKS) {
    const int idx = (blk - CONV_BLKS) * 256 + threadIdx.x;
    if (idx >= BB * NH * NCH) return;
    const int c = idx & (NCH - 1);
    const int bh = idx >> 4;
    const int b = bh >> 4, h = bh & (NH - 1);
    const float A = -__expf(A_log[h]);
    float run = 0.f;
    for (int i = 0; i < QC; ++i) {
      run += A * dtv[(size_t)(b * LL + c * QC + i) * NH + h];
      clog[(size_t)bh * LL + c * QC + i] = run;
    }
    return;
  }
  const int idx = blk * 256 + threadIdx.x;
  const int c = idx % CONVDIM;
  const int bl = idx / CONVDIM;
  const int l = bl & (LL - 1);
  const float w0 = conv_w[c * 4 + 0], w1 = conv_w[c * 4 + 1];
  const float w2 = conv_w[c * 4 + 2], w3 = conv_w[c * 4 + 3];
  const float* base = zx + (size_t)bl * DINPROJ + DINNER + c;
  float acc = conv_b[c];
  acc = fmaf(base[0], w3, acc);
  if (l >= 1) acc = fmaf(base[-1 * DINPROJ], w2, acc);
  if (l >= 2) acc = fmaf(base[-2 * DINPROJ], w1, acc);
  if (l >= 3) acc = fmaf(base[-3 * DINPROJ], w0, acc);
  const float s = acc / (1.f + expf(-acc));
  if (c < DINNER)                    xy[(size_t)bl * DINNER + c] = s;
  else if (c < DINNER + NS)          Bm[bl * NS + (c - DINNER)] = s;
  else                               Cm[bl * NS + (c - DINNER - NS)] = s;
}

// ---- SSD intra-chunk via bf16 MFMA ----
__global__ __launch_bounds__(256) void ssd_intra(const float* __restrict__ xy,
                                                 const float* __restrict__ Bm,
                                                 const float* __restrict__ Cm,
                                                 const float* __restrict__ dtv,
                                                 const float* __restrict__ clog,
                                                 float* __restrict__ zx,
                                                 float* __restrict__ S) {
  __shared__ __align__(16) ushort sC[64 * LSTR];
  __shared__ __align__(16) ushort sB[64 * LSTR];
  __shared__ __align__(16) ushort sBT[64 * LSTR];
  __shared__ __align__(16) ushort sXT[128 * LSTR];
  __shared__ __align__(16) ushort sP[64 * LSTR];
  __shared__ float scl[QC], sdt[QC], swdt[QC];
  const int blk = blockIdx.x;
  const int bh = blk >> 4, c = blk & (NCH - 1);
  const int b = bh >> 4, h = bh & (NH - 1);
  const int t0 = c * QC;
  const int tid = threadIdx.x;
  const int w = tid >> 6, lane = tid & 63, l15 = lane & 15, lg = lane >> 4;

  if (tid < QC) {
    const float cl = clog[(size_t)bh * LL + t0 + tid];
    const float clend = clog[(size_t)bh * LL + t0 + QC - 1];
    const float dt = dtv[(size_t)(b * LL + t0 + tid) * NH + h];
    scl[tid] = cl; sdt[tid] = dt;
    swdt[tid] = __expf(clend - cl) * dt;
  }
  __syncthreads();

  const float* Bg = Bm + (size_t)(b * LL + t0) * NS;
  const float* Cg = Cm + (size_t)(b * LL + t0) * NS;
#pragma unroll
  for (int j = 0; j < 4; ++j) {
    const int f = j * 256 + tid;
    const int r = f >> 4, c4 = f & 15;
    const float4 bv = *(const float4*)(Bg + r * NS + c4 * 4);
    const float4 cv = *(const float4*)(Cg + r * NS + c4 * 4);
    *(uint2*)(sB + r * LSTR + c4 * 4) = make_uint2(bfpair(bv.x, bv.y), bfpair(bv.z, bv.w));
    *(uint2*)(sC + r * LSTR + c4 * 4) = make_uint2(bfpair(cv.x, cv.y), bfpair(cv.z, cv.w));
  }
  {
    const int n = tid & 63, sg = tid >> 6;
    float bw[16];
#pragma unroll
    for (int j = 0; j < 16; ++j) {
      const int s = sg * 16 + j;
      bw[j] = swdt[s] * Bg[(size_t)s * NS + n];
    }
    *(uint4*)(sBT + n * LSTR + sg * 16) = pack8(bw);
    *(uint4*)(sBT + n * LSTR + sg * 16 + 8) = pack8(bw + 8);
  }
  {
    const int p = tid & 127, sh = tid >> 7;
    const float* xg = xy + (size_t)(b * LL + t0 + sh * 32) * DINNER + h * HD + p;
    float xv[32];
#pragma unroll
    for (int j = 0; j < 32; ++j) xv[j] = xg[(size_t)j * DINNER];
#pragma unroll
    for (int q = 0; q < 4; ++q)
      *(uint4*)(sXT + p * LSTR + sh * 32 + q * 8) = pack8(xv + q * 8);
  }
  __syncthreads();

  f32x4 g[4] = {};
#pragma unroll
  for (int ks = 0; ks < 2; ++ks) {
    const bf16x8 ca = *(const bf16x8*)((const char*)sC + (w * 16 + l15) * 144 + ks * 64 + lg * 16);
#pragma unroll
    for (int ni = 0; ni < 4; ++ni) {
      const bf16x8 bb = *(const bf16x8*)((const char*)sB + (ni * 16 + l15) * 144 + ks * 64 + lg * 16);
      g[ni] = __builtin_amdgcn_mfma_f32_16x16x32_bf16(ca, bb, g[ni], 0, 0, 0);
    }
  }
#pragma unroll
  for (int ni = 0; ni < 4; ++ni) {
    const int s = ni * 16 + l15;
    const float cls = scl[s], dts = sdt[s];
#pragma unroll
    for (int j = 0; j < 4; ++j) {
      const int t = w * 16 + lg * 4 + j;
      const float v = (s <= t) ? g[ni][j] * __expf(scl[t] - cls) * dts : 0.f;
      sP[t * LSTR + s] = bf1(v);
    }
  }
  f32x4 sa[2][4] = {};
#pragma unroll
  for (int ks = 0; ks < 2; ++ks) {
    const bf16x8 a0 = *(const bf16x8*)((const char*)sXT + (w * 32 + l15) * 144 + ks * 64 + lg * 16);
    const bf16x8 a1 = *(const bf16x8*)((const char*)sXT + (w * 32 + 16 + l15) * 144 + ks * 64 + lg * 16);
#pragma unroll
    for (int nj = 0; nj < 4; ++nj) {
      const bf16x8 bb = *(const bf16x8*)((const char*)sBT + (nj * 16 + l15) * 144 + ks * 64 + lg * 16);
      sa[0][nj] = __builtin_amdgcn_mfma_f32_16x16x32_bf16(a0, bb, sa[0][nj], 0, 0, 0);
      sa[1][nj] = __builtin_amdgcn_mfma_f32_16x16x32_bf16(a1, bb, sa[1][nj], 0, 0, 0);
    }
  }
  float* Sg = S + (size_t)blk * (HD * NS);
#pragma unroll
  for (int mi = 0; mi < 2; ++mi)
#pragma unroll
    for (int nj = 0; nj < 4; ++nj)
#pragma unroll
      for (int j = 0; j < 4; ++j)
        Sg[(size_t)(w * 32 + mi * 16 + lg * 4 + j) * NS + nj * 16 + l15] = sa[mi][nj][j];
  __syncthreads();

  f32x4 y[8] = {};
#pragma unroll
  for (int ks = 0; ks < 2; ++ks) {
    const bf16x8 pa = *(const bf16x8*)((const char*)sP + (w * 16 + l15) * 144 + ks * 64 + lg * 16);
#pragma unroll
    for (int ni = 0; ni < 8; ++ni) {
      const bf16x8 xb = *(const bf16x8*)((const char*)sXT + (ni * 16 + l15) * 144 + ks * 64 + lg * 16);
      y[ni] = __builtin_amdgcn_mfma_f32_16x16x32_bf16(pa, xb, y[ni], 0, 0, 0);
    }
  }
  float* yg = zx + (size_t)(b * LL + t0) * DINPROJ + DINNER + h * HD;
#pragma unroll
  for (int ni = 0; ni < 8; ++ni)
#pragma unroll
    for (int j = 0; j < 4; ++j)
      yg[(size_t)(w * 16 + lg * 4 + j) * DINPROJ + ni * 16 + l15] = y[ni][j];
}

// ---- inter-chunk scan over chunk states ----
__global__ __launch_bounds__(256) void ssd_scan(float* __restrict__ S,
                                                const float* __restrict__ clog) {
  const int idx = blockIdx.x * 256 + threadIdx.x;
  const int pn = idx & (HD * NS - 1);
  const int bh = idx >> 13;
  float* Sp = S + (size_t)bh * NCH * (HD * NS) + pn;
  const float* cl = clog + (size_t)bh * LL;
  float H = 0.f;
#pragma unroll
  for (int c = 0; c < NCH; ++c) {
    const float dec = __expf(cl[c * QC + QC - 1]);
    const float s = Sp[(size_t)c * (HD * NS)];
    Sp[(size_t)c * (HD * NS)] = H;
    H = dec * H + s;
  }
}

// ---- y = y_intra + exp(cl)*C.H^T + D*x (bf16 MFMA, in place on xy) ----
__global__ __launch_bounds__(256) void ssd_out(float* __restrict__ xy,
                                               const float* __restrict__ zx,
                                               const float* __restrict__ Cm,
                                               const float* __restrict__ clog,
                                               const float* __restrict__ S,
                                               const float* __restrict__ Dp_) {
  __shared__ __align__(16) ushort sC[64 * LSTR];
  __shared__ __align__(16) ushort sH[128 * LSTR];
  __shared__ float sE[QC];
  const int blk = blockIdx.x;
  const int bh = blk >> 4, c = blk & (NCH - 1);
  const int b = bh >> 4, h = bh & (NH - 1);
  const int t0 = c * QC;
  const int tid = threadIdx.x;
  const int w = tid >> 6, lane = tid & 63, l15 = lane & 15, lg = lane >> 4;

  if (tid < QC) sE[tid] = __expf(clog[(size_t)bh * LL + t0 + tid]);
  const float* Cg = Cm + (size_t)(b * LL + t0) * NS;
#pragma unroll
  for (int j = 0; j < 4; ++j) {
    const int f = j * 256 + tid, r = f >> 4, c4 = f & 15;
    const float4 cv = *(const float4*)(Cg + r * NS + c4 * 4);
    *(uint2*)(sC + r * LSTR + c4 * 4) = make_uint2(bfpair(cv.x, cv.y), bfpair(cv.z, cv.w));
  }
  const float* Hg = S + (size_t)blk * (HD * NS);
#pragma unroll
  for (int j = 0; j < 8; ++j) {
    const int f = j * 256 + tid, p = f >> 4, n4 = f & 15;
    const float4 hv = *(const float4*)(Hg + (size_t)p * NS + n4 * 4);
    *(uint2*)(sH + p * LSTR + n4 * 4) = make_uint2(bfpair(hv.x, hv.y), bfpair(hv.z, hv.w));
  }
  __syncthreads();

  f32x4 y2[8] = {};
#pragma unroll
  for (int ks = 0; ks < 2; ++ks) {
    const bf16x8 ca = *(const bf16x8*)((const char*)sC + (w * 16 + l15) * 144 + ks * 64 + lg * 16);
#pragma unroll
    for (int ni = 0; ni < 8; ++ni) {
      const bf16x8 hb = *(const bf16x8*)((const char*)sH + (ni * 16 + l15) * 144 + ks * 64 + lg * 16);
      y2[ni] = __builtin_amdgcn_mfma_f32_16x16x32_bf16(ca, hb, y2[ni], 0, 0, 0);
    }
  }
  const float Dv = Dp_[h];
#pragma unroll
  for (int ni = 0; ni < 8; ++ni) {
    const int p = ni * 16 + l15;
#pragma unroll
    for (int j = 0; j < 4; ++j) {
      const int t = w * 16 + lg * 4 + j;
      const size_t row = (size_t)(b * LL + t0 + t);
      const float yi = zx[row * DINPROJ + DINNER + h * HD + p];
      float* xp = xy + row * DINNER + h * HD + p;
      *xp = yi + sE[t] * y2[ni][j] + Dv * (*xp);
    }
  }
}

// ---- y *= silu(z); RMSNorm; emit packed bf16 128-row tiles for out-proj ----
__global__ __launch_bounds__(256) void gate_norm_pack(const float* __restrict__ xy,
                                                      const float* __restrict__ zx,
                                                      const float* __restrict__ nw,
                                                      ushort* __restrict__ yP) {
  __shared__ float red[4];
  const int m = blockIdx.x;
  const int t = threadIdx.x;
  const float* yrow = xy + (size_t)m * DINNER;
  const float* zrow = zx + (size_t)m * DINPROJ;
  const int e = t * 8;
  const float4 y0 = *(const float4*)(yrow + e), y1 = *(const float4*)(yrow + e + 4);
  const float4 z0 = *(const float4*)(zrow + e), z1 = *(const float4*)(zrow + e + 4);
  float v[8];
  v[0] = y0.x * (z0.x / (1.f + expf(-z0.x)));
  v[1] = y0.y * (z0.y / (1.f + expf(-z0.y)));
  v[2] = y0.z * (z0.z / (1.f + expf(-z0.z)));
  v[3] = y0.w * (z0.w / (1.f + expf(-z0.w)));
  v[4] = y1.x * (z1.x / (1.f + expf(-z1.x)));
  v[5] = y1.y * (z1.y / (1.f + expf(-z1.y)));
  v[6] = y1.z * (z1.z / (1.f + expf(-z1.z)));
  v[7] = y1.w * (z1.w / (1.f + expf(-z1.w)));
  float ss = 0.f;
#pragma unroll
  for (int j = 0; j < 8; ++j) ss += v[j] * v[j];
#pragma unroll
  for (int off = 32; off; off >>= 1) ss += __shfl_down(ss, off);
  const int lane = t & 63, wid = t >> 6;
  if (lane == 0) red[wid] = ss;
  __syncthreads();
  const float tot = red[0] + red[1] + red[2] + red[3];
  const float rstd = rsqrtf(tot * (1.f / DINNER) + 1e-5f);
  const float4 w0 = *(const float4*)(nw + e), w1 = *(const float4*)(nw + e + 4);
  v[0] *= rstd * w0.x; v[1] *= rstd * w0.y; v[2] *= rstd * w0.z; v[3] *= rstd * w0.w;
  v[4] *= rstd * w1.x; v[5] *= rstd * w1.y; v[6] *= rstd * w1.z; v[7] *= rstd * w1.w;
  // 128-row tile pack: tile (m>>7)*64 + (t>>2), row r=m&127, slot s=(t^(r>>1))&3
  const int r = m & 127;
  const int tk = t >> 2;
  const int s = (t ^ (r >> 1)) & 3;
  uint4 pk;
  pk.x = bfpair(v[0], v[1]); pk.y = bfpair(v[2], v[3]);
  pk.z = bfpair(v[4], v[5]); pk.w = bfpair(v[6], v[7]);
  *(uint4*)(yP + (size_t)((m >> 7) * 64 + tk) * 4096 + r * 32 + s * 8) = pk;
}

extern "C" void kernel_launch(void* const* d_in, const int* in_sizes, int n_in,
                              void* d_out, int out_size, void* d_ws, size_t ws_size,
                              hipStream_t stream) {
  const float* hs      = (const float*)d_in[0];
  const float* W_in    = (const float*)d_in[1];
  const float* conv_w  = (const float*)d_in[2];
  const float* conv_b  = (const float*)d_in[3];
  const float* dt_bias = (const float*)d_in[4];
  const float* A_log   = (const float*)d_in[5];
  const float* D_param = (const float*)d_in[6];
  const float* norm_w  = (const float*)d_in[7];
  const float* W_out   = (const float*)d_in[8];
  float* out = (float*)d_out;

  float* ws   = (float*)d_ws;
  float* zx   = ws;                                      // (2048, 4240)
  float* xy   = zx + (size_t)BB * LL * DINPROJ;          // (2048, 2048)
  float* Bm   = xy + (size_t)BB * LL * DINNER;           // (2048, 64)
  float* Cm   = Bm + (size_t)BB * LL * NS;               // (2048, 64)
  float* dtv  = Cm + (size_t)BB * LL * NS;               // (2048, 16)
  float* clog = dtv + (size_t)BB * LL * NH;              // (32, 1024)
  float* S    = clog + (size_t)BB * LL * NH;             // (512, 8192)
  ushort* hsP   = (ushort*)(S + (size_t)512 * 8192);     // 2048x1024 bf16
  ushort* WinP  = hsP + (size_t)2048 * 1024;             // 4224x1024 bf16
  ushort* WoutP = WinP + (size_t)4224 * 1024;            // 1024x2048 bf16
  ushort* yP    = WoutP + (size_t)1024 * 2048;           // 2048x2048 bf16 (128-row tiles)
  float* Cpart  = (float*)(yP + (size_t)2048 * 2048);    // 4 x 2048x1024 fp32 = 33.6 MB

  const int M = BB * LL;

  prep_kernel<<<PREP_HS + PREP_WIN + PREP_WOUT + M, 256, 0, stream>>>(
      hs, W_in, W_out, dt_bias, hsP, WinP, WoutP, dtv);
  mfma_gemm<<<dim3(33, 16), 256, 0, stream>>>(hsP, WinP, zx, DINPROJ, 32, 32, 0);
  conv_cumlog<<<CONV_BLKS + 2, 256, 0, stream>>>(zx, conv_w, conv_b, xy, Bm, Cm, dtv, A_log, clog);
  ssd_intra<<<BB * NH * NCH, 256, 0, stream>>>(xy, Bm, Cm, dtv, clog, zx, S);
  ssd_scan<<<(BB * NH * HD * NS) / 256, 256, 0, stream>>>(S, clog);
  ssd_out<<<BB * NH * NCH, 256, 0, stream>>>(xy, zx, Cm, clog, S, D_param);
  gate_norm_pack<<<M, 256, 0, stream>>>(xy, zx, norm_w, yP);
  mfma_gemm<<<dim3(8, 16, 4), 256, 0, stream>>>(yP, WoutP, Cpart, DMODEL, 64, 16,
                                                (size_t)DMODEL * BB * LL);
  reduce4<<<(BB * LL * DMODEL) / 1024, 256, 0, stream>>>(Cpart, out);
}